// Round 15
// baseline (211.850 us; speedup 1.0000x reference)
//
#include <hip/hip_runtime.h>
#include <hip/hip_bf16.h>

#define B_ 2
#define S_ 2048
#define D_ 1024
#define H_ 16
#define KV_ 4
#define HD_ 64
#define G_ (H_ / KV_)
#define NCAT 2816          // 2*H*HD + 2*KV*HD + KV*HD
#define VOFF 2560          // col offset of V block in fused QKV output

typedef __attribute__((ext_vector_type(8))) short short8;
typedef __attribute__((ext_vector_type(4))) short short4v;
typedef __attribute__((ext_vector_type(2))) int int2v;
typedef __attribute__((ext_vector_type(4))) int int4v;
typedef __attribute__((ext_vector_type(4))) float floatx4;

using gvoid_p = const __attribute__((address_space(1))) void*;
using lvoid_p = __attribute__((address_space(3))) void*;

__device__ inline void gload_lds16(const short* g, short* l) {
    __builtin_amdgcn_global_load_lds((gvoid_p)(const void*)g, (lvoid_p)(void*)l, 16, 0, 0);
}

__device__ inline int cvt_pk_bf16(float lo, float hi) {
    int r;
    asm volatile("v_cvt_pk_bf16_f32 %0, %1, %2" : "=v"(r) : "v"(lo), "v"(hi));
    return r;
}

__device__ inline float bf16lo(unsigned u) {
    return __builtin_bit_cast(float, u << 16);
}
__device__ inline float bf16hi(unsigned u) {
    return __builtin_bit_cast(float, u & 0xffff0000u);
}

// ---------------- fused fp32 -> bf16 convert (5 segments, float4 vectorized) -------------
__global__ void cvt5_kernel(const float* s0, const float* s1, const float* s2,
                            const float* s3, const float* s4,
                            __hip_bfloat16* d0, __hip_bfloat16* d1, __hip_bfloat16* d2,
                            __hip_bfloat16* d3, __hip_bfloat16* d4,
                            int n0, int n1, int n2, int n3, int n4) {
    const float* s; __hip_bfloat16* d; int n;
    switch (blockIdx.y) {
        case 0: s = s0; d = d0; n = n0; break;
        case 1: s = s1; d = d1; n = n1; break;
        case 2: s = s2; d = d2; n = n2; break;
        case 3: s = s3; d = d3; n = n3; break;
        default: s = s4; d = d4; n = n4; break;
    }
    int nv = n >> 2;
    for (int i = blockIdx.x * blockDim.x + threadIdx.x; i < nv;
         i += gridDim.x * blockDim.x) {
        floatx4 v = ((const floatx4*)s)[i];
        short4v o;
#pragma unroll
        for (int e = 0; e < 4; ++e) {
            __hip_bfloat16 hh = __float2bfloat16(v[e]);
            o[e] = __builtin_bit_cast(short, hh);
        }
        ((short4v*)d)[i] = o;
    }
}

// ---------------- QKV GEMM with FUSED RMSNorm+RoPE epilogue (unchanged r13) --------------
__global__ __launch_bounds__(256) void gemm_qkv_fused(const short* __restrict__ A,
                                                      const short* __restrict__ Bm,
                                                      __hip_bfloat16* __restrict__ qout,
                                                      __hip_bfloat16* __restrict__ kout,
                                                      __hip_bfloat16* __restrict__ vout,
                                                      const float* __restrict__ freqs,
                                                      const float* __restrict__ qnw,
                                                      const float* __restrict__ knw,
                                                      int M, int N, int K) {
    __shared__ __align__(16) short As[2][128 * 32];
    __shared__ __align__(16) short Bs[2][128 * 32];
    int tid = threadIdx.x;
    int wid = tid >> 6, lane = tid & 63;
    int wr = wid >> 1, wc = wid & 1;
    int r = lane & 15, kq = lane >> 4;

    int nwg = gridDim.x * gridDim.y;
    int orig = blockIdx.y * gridDim.x + blockIdx.x;
    int wg = (orig & 7) * (nwg >> 3) + (orig >> 3);
    int bx = wg % gridDim.x, by = wg / gridDim.x;

    long m0 = (long)by * 128;
    long n0 = (long)bx * 128;

    const short* gA0 = A + (m0 + (tid >> 2)) * (long)K + (tid & 3) * 8;
    const short* gA1 = A + (m0 + 64 + (tid >> 2)) * (long)K + (tid & 3) * 8;
    const short* gB0 = Bm + (n0 + (tid >> 2)) * (long)K + (tid & 3) * 8;
    const short* gB1 = Bm + (n0 + 64 + (tid >> 2)) * (long)K + (tid & 3) * 8;

    auto stage = [&](int buf, int k0) {
        gload_lds16(gA0 + k0, &As[buf][wid * 512]);
        gload_lds16(gA1 + k0, &As[buf][2048 + wid * 512]);
        gload_lds16(gB0 + k0, &Bs[buf][wid * 512]);
        gload_lds16(gB1 + k0, &Bs[buf][2048 + wid * 512]);
    };

    floatx4 acc[4][4];
#pragma unroll
    for (int i = 0; i < 4; ++i)
#pragma unroll
        for (int j = 0; j < 4; ++j) acc[i][j] = {0.f, 0.f, 0.f, 0.f};

    int nt = K >> 5;
    stage(0, 0);
    for (int t = 0; t < nt; ++t) {
        int cur = t & 1;
        __builtin_amdgcn_s_barrier();
        if (t + 1 < nt) {
            stage(cur ^ 1, (t + 1) << 5);
            asm volatile("s_waitcnt vmcnt(4)" ::: "memory");
        } else {
            asm volatile("s_waitcnt vmcnt(0)" ::: "memory");
        }
        __builtin_amdgcn_sched_barrier(0);
        __builtin_amdgcn_s_barrier();
        short8 a[4], b[4];
#pragma unroll
        for (int mi = 0; mi < 4; ++mi)
            a[mi] = *(const short8*)&As[cur][(wr * 64 + mi * 16 + r) * 32 + kq * 8];
#pragma unroll
        for (int ni = 0; ni < 4; ++ni)
            b[ni] = *(const short8*)&Bs[cur][(wc * 64 + ni * 16 + r) * 32 + kq * 8];
#pragma unroll
        for (int mi = 0; mi < 4; ++mi)
#pragma unroll
            for (int ni = 0; ni < 4; ++ni)
                acc[mi][ni] = __builtin_amdgcn_mfma_f32_16x16x32_bf16(
                    a[mi], b[ni], acc[mi][ni], 0, 0, 0);
    }

    int col_l = lane & 15;
    int gbase = (int)n0 + wc * 64;
    int par = col_l & 1;
    if (gbase < VOFF) {
        const float* wnorm = (gbase < 2048) ? qnw : knw;
        float wv4[4];
        int fo[4];
#pragma unroll
        for (int ni = 0; ni < 4; ++ni) {
            wv4[ni] = wnorm[ni * 16 + col_l];
            fo[ni] = ni * 16 + (col_l >> 1) * 2;
        }
        __hip_bfloat16* outp;
        long tstride;
        int cbase;
        if (gbase < 2048) { outp = qout; tstride = 2048; cbase = gbase; }
        else              { outp = kout; tstride = 512;  cbase = gbase - 2048; }
#pragma unroll
        for (int mi = 0; mi < 4; ++mi) {
#pragma unroll
            for (int j = 0; j < 4; ++j) {
                int t = (int)m0 + wr * 64 + mi * 16 + kq * 4 + j;
                float ss = 0.f;
#pragma unroll
                for (int ni = 0; ni < 4; ++ni)
                    ss = fmaf(acc[mi][ni][j], acc[mi][ni][j], ss);
                ss += __shfl_xor(ss, 1); ss += __shfl_xor(ss, 2);
                ss += __shfl_xor(ss, 4); ss += __shfl_xor(ss, 8);
                float rr = rsqrtf(ss * (1.f / 64.f) + 1e-6f);
                const float* fb = freqs + (long)(t & (S_ - 1)) * 64;
                __hip_bfloat16* orow = outp + (long)t * tstride + cbase;
#pragma unroll
                for (int ni = 0; ni < 4; ++ni) {
                    float xv = acc[mi][ni][j] * rr * wv4[ni];
                    float pp = __shfl_xor(xv, 1);
                    float cc = fb[fo[ni]], sn = fb[fo[ni] + 1];
                    float y = par ? fmaf(pp, sn, xv * cc) : fmaf(xv, cc, -(pp * sn));
                    orow[ni * 16 + col_l] = __float2bfloat16(y);
                }
            }
        }
    } else {
        int kvv = (gbase - VOFF) >> 6;
#pragma unroll
        for (int mi = 0; mi < 4; ++mi) {
#pragma unroll
            for (int j = 0; j < 4; ++j) {
                int t = (int)m0 + wr * 64 + mi * 16 + kq * 4 + j;
                int bb = t >> 11, st = t & (S_ - 1);
                __hip_bfloat16* vcol = vout + ((long)(bb * KV_ + kvv) * 64) * S_ + st;
#pragma unroll
                for (int ni = 0; ni < 4; ++ni)
                    vcol[(long)(ni * 16 + col_l) * S_] = __float2bfloat16(acc[mi][ni][j]);
            }
        }
    }
}

// ---------------- NT GEMM (out-projection), unchanged ----------
template <typename OutT>
__global__ __launch_bounds__(256) void gemm_bt_lds(const short* __restrict__ A,
                                                   const short* __restrict__ Bm,
                                                   OutT* __restrict__ C,
                                                   int M, int N, int K) {
    __shared__ __align__(16) short As[2][128 * 32];
    __shared__ __align__(16) short Bs[2][128 * 32];
    int tid = threadIdx.x;
    int wid = tid >> 6, lane = tid & 63;
    int wr = wid >> 1, wc = wid & 1;
    int r = lane & 15, kq = lane >> 4;

    int nwg = gridDim.x * gridDim.y;
    int orig = blockIdx.y * gridDim.x + blockIdx.x;
    int wg = (orig & 7) * (nwg >> 3) + (orig >> 3);
    int bx = wg % gridDim.x, by = wg / gridDim.x;

    long m0 = (long)by * 128;
    long n0 = (long)bx * 128;

    const short* gA0 = A + (m0 + (tid >> 2)) * (long)K + (tid & 3) * 8;
    const short* gA1 = A + (m0 + 64 + (tid >> 2)) * (long)K + (tid & 3) * 8;
    const short* gB0 = Bm + (n0 + (tid >> 2)) * (long)K + (tid & 3) * 8;
    const short* gB1 = Bm + (n0 + 64 + (tid >> 2)) * (long)K + (tid & 3) * 8;

    auto stage = [&](int buf, int k0) {
        gload_lds16(gA0 + k0, &As[buf][wid * 512]);
        gload_lds16(gA1 + k0, &As[buf][2048 + wid * 512]);
        gload_lds16(gB0 + k0, &Bs[buf][wid * 512]);
        gload_lds16(gB1 + k0, &Bs[buf][2048 + wid * 512]);
    };

    floatx4 acc[4][4];
#pragma unroll
    for (int i = 0; i < 4; ++i)
#pragma unroll
        for (int j = 0; j < 4; ++j) acc[i][j] = {0.f, 0.f, 0.f, 0.f};

    int nt = K >> 5;
    stage(0, 0);
    for (int t = 0; t < nt; ++t) {
        int cur = t & 1;
        __builtin_amdgcn_s_barrier();
        if (t + 1 < nt) {
            stage(cur ^ 1, (t + 1) << 5);
            asm volatile("s_waitcnt vmcnt(4)" ::: "memory");
        } else {
            asm volatile("s_waitcnt vmcnt(0)" ::: "memory");
        }
        __builtin_amdgcn_sched_barrier(0);
        __builtin_amdgcn_s_barrier();
        short8 a[4], b[4];
#pragma unroll
        for (int mi = 0; mi < 4; ++mi)
            a[mi] = *(const short8*)&As[cur][(wr * 64 + mi * 16 + r) * 32 + kq * 8];
#pragma unroll
        for (int ni = 0; ni < 4; ++ni)
            b[ni] = *(const short8*)&Bs[cur][(wc * 64 + ni * 16 + r) * 32 + kq * 8];
#pragma unroll
        for (int mi = 0; mi < 4; ++mi)
#pragma unroll
            for (int ni = 0; ni < 4; ++ni)
                acc[mi][ni] = __builtin_amdgcn_mfma_f32_16x16x32_bf16(
                    a[mi], b[ni], acc[mi][ni], 0, 0, 0);
    }
    int col_l = lane & 15, row_l = (lane >> 4) * 4;
#pragma unroll
    for (int mi = 0; mi < 4; ++mi)
#pragma unroll
        for (int ni = 0; ni < 4; ++ni) {
            long col = n0 + wc * 64 + ni * 16 + col_l;
            long row0 = m0 + wr * 64 + mi * 16 + row_l;
#pragma unroll
            for (int j = 0; j < 4; ++j) {
                float v = acc[mi][ni][j];
                if constexpr (__is_same(OutT, float))
                    C[(row0 + j) * N + col] = v;
                else
                    C[(row0 + j) * N + col] = __float2bfloat16(v);
            }
        }
}

// ---------------- differential causal attention: 512 threads, QBLK=128, KVBLK=64 --------
// Grid = 512 blocks; xcd = raw&7 = (b,kv). 8 waves each own 16 q-rows. KVBLK=64:
// half the iterations/barriers of r14, same MFMA. K: gload_lds TRIPLE buffer
// Ks[3][64][128] (2 chunks/thread, source-XOR slot swizzle; nt*16 = 0 mod 8 keeps
// the r-based read involution valid). V: reg-staged dbuf Vt[2][64][72], 1 chunk/thread
// (all 8 waves). vmcnt(2) steady (2 K-DMAs of t+1 in flight). PV: two 32-k windows
// per tile, each the proven pa/vb sigma-pairing, accumulated into the same acc.
// Pairing (64-k units): qtA=p (2p+2 tiles), qtB=15-p (32-2p); e=0: qtA full + qtB
// prefix (15-2p); e=1: qtB suffix (17). Both halves = 17 tiles, perfectly uniform.
__global__ __launch_bounds__(512, 4) void attn_kernel(const short* __restrict__ qb,
                                                      const short* __restrict__ kbuf,
                                                      const short* __restrict__ vtb,
                                                      __hip_bfloat16* __restrict__ ob,
                                                      unsigned* __restrict__ part,
                                                      float* __restrict__ lpart,
                                                      const float* __restrict__ lam_p) {
    __shared__ __align__(16) short Ks[3][64][128];
    __shared__ __align__(16) short Vt[2][64][72];

    int tid = threadIdx.x, w = tid >> 6, lane = tid & 63;
    int raw = (int)blockIdx.x;
    int xcd = raw & 7;
    int kv = xcd & 3, b = xcd >> 2;
    int i5 = raw >> 3;                  // [0,64)
    int x = i5 & 15, hh = i5 >> 4;
    int h = kv * G_ + hh;
    int p = x >> 1, e = x & 1;
    int qtA = p, qtB = 15 - p;          // 128-row q-tiles
    int r = lane & 15, kq = lane >> 4;
    float lam = lam_p[0];

    floatx4 acc[2][4];
    floatx4 accl[2];
    short8 qa[2][2];

    const short* vbase = vtb + (long)(b * KV_ + kv) * 64 * S_;
    const float c1 = 0.18033688f, nc4 = -3.7570e-7f, zoff = -17.3123405f;
    const short one_bf = (short)0x3F80;
    short8 ones8 = {one_bf, one_bf, one_bf, one_bf, one_bf, one_bf, one_bf, one_bf};

    // K staging: 64x128 tile = 1024 16B-chunks, 2/thread (rows krow, krow+32; same slot).
    int krow = tid >> 4, kcs = ((tid & 15) ^ (krow & 7)) * 8;
    const short* kgb = kbuf + ((long)b * S_ * KV_ + kv) * 128;
    int vd = tid >> 3, vch = tid & 7;   // V: 64x64 = 512 chunks, 1/thread

    auto issueK = [&](int buf, int ki) {
        long rb = (long)(ki * 64) * (KV_ * 128);
        gload_lds16(kgb + rb + (long)krow * (KV_ * 128) + kcs, &Ks[buf][0][0] + w * 512);
        gload_lds16(kgb + rb + (long)(krow + 32) * (KV_ * 128) + kcs,
                    &Ks[buf][0][0] + 4096 + w * 512);
    };
    auto loadV = [&](int kb) {
        return *(const short8*)(vbase + (long)vd * S_ + kb + vch * 8);
    };

    auto reset_acc = [&]() {
#pragma unroll
        for (int m = 0; m < 2; ++m) {
            accl[m] = {0.f, 0.f, 0.f, 0.f};
#pragma unroll
            for (int dt = 0; dt < 4; ++dt) acc[m][dt] = {0.f, 0.f, 0.f, 0.f};
        }
    };
    auto load_q = [&](int q0) {
        const short* qrow = qb + ((long)(b * S_ + q0 + r) * H_ + h) * 128;
        qa[0][0] = *(const short8*)(qrow + kq * 8);
        qa[0][1] = *(const short8*)(qrow + 32 + kq * 8);
        qa[1][0] = *(const short8*)(qrow + 64 + kq * 8);
        qa[1][1] = *(const short8*)(qrow + 96 + kq * 8);
    };

    auto tile_compute = [&](int bk, int cv, int kb, int q0, bool domask) {
        int rel = q0 + r - kb;
        // V fragments (map-independent), sigma-order per 32-k window
        short8 vbL[4], vbH[4];
#pragma unroll
        for (int dt = 0; dt < 4; ++dt) {
            const short* vrow = &Vt[cv][dt * 16 + r][0];
            int2v va = *(const int2v*)(vrow + 4 * kq);
            int2v vbb = *(const int2v*)(vrow + 16 + 4 * kq);
            int2v vc = *(const int2v*)(vrow + 32 + 4 * kq);
            int2v vdd = *(const int2v*)(vrow + 48 + 4 * kq);
            vbL[dt] = __builtin_bit_cast(short8, int4v{va[0], va[1], vbb[0], vbb[1]});
            vbH[dt] = __builtin_bit_cast(short8, int4v{vc[0], vc[1], vdd[0], vdd[1]});
        }
#pragma unroll
        for (int m = 0; m < 2; ++m) {
            floatx4 sacc[4];
            __builtin_amdgcn_s_setprio(1);
#pragma unroll
            for (int nt = 0; nt < 4; ++nt) {
                sacc[nt] = {0.f, 0.f, 0.f, 0.f};
                const short* row = &Ks[bk][nt * 16 + r][0];
                short8 a0 = *(const short8*)(row + (((m * 8) + kq) ^ (r & 7)) * 8);
                short8 a1 = *(const short8*)(row + (((m * 8) + 4 + kq) ^ (r & 7)) * 8);
                sacc[nt] = __builtin_amdgcn_mfma_f32_16x16x32_bf16(a0, qa[m][0], sacc[nt], 0, 0, 0);
                sacc[nt] = __builtin_amdgcn_mfma_f32_16x16x32_bf16(a1, qa[m][1], sacc[nt], 0, 0, 0);
            }
            __builtin_amdgcn_s_setprio(0);
            float pv[4][4];
#pragma unroll
            for (int nt = 0; nt < 4; ++nt)
#pragma unroll
                for (int j = 0; j < 4; ++j) {
                    float rawv = sacc[nt][j];
                    float r2 = rawv * rawv;
                    float z = fmaf(rawv, fmaf(r2, nc4, c1), zoff);
                    pv[nt][j] = __builtin_amdgcn_exp2f(z);
                }
            if (domask) {
#pragma unroll
                for (int nt = 0; nt < 4; ++nt)
#pragma unroll
                    for (int j = 0; j < 4; ++j)
                        if (nt * 16 + kq * 4 + j > rel) pv[nt][j] = 0.f;
            }
            int d0 = cvt_pk_bf16(pv[0][0], pv[0][1]);
            int d1 = cvt_pk_bf16(pv[0][2], pv[0][3]);
            int d2 = cvt_pk_bf16(pv[1][0], pv[1][1]);
            int d3 = cvt_pk_bf16(pv[1][2], pv[1][3]);
            short8 paL = __builtin_bit_cast(short8, int4v{d0, d1, d2, d3});
            int d4 = cvt_pk_bf16(pv[2][0], pv[2][1]);
            int d5 = cvt_pk_bf16(pv[2][2], pv[2][3]);
            int d6 = cvt_pk_bf16(pv[3][0], pv[3][1]);
            int d7 = cvt_pk_bf16(pv[3][2], pv[3][3]);
            short8 paH = __builtin_bit_cast(short8, int4v{d4, d5, d6, d7});
            __builtin_amdgcn_s_setprio(1);
#pragma unroll
            for (int dt = 0; dt < 4; ++dt) {
                acc[m][dt] = __builtin_amdgcn_mfma_f32_16x16x32_bf16(
                    paL, vbL[dt], acc[m][dt], 0, 0, 0);
                acc[m][dt] = __builtin_amdgcn_mfma_f32_16x16x32_bf16(
                    paH, vbH[dt], acc[m][dt], 0, 0, 0);
            }
            accl[m] = __builtin_amdgcn_mfma_f32_16x16x32_bf16(paL, ones8, accl[m], 0, 0, 0);
            accl[m] = __builtin_amdgcn_mfma_f32_16x16x32_bf16(paH, ones8, accl[m], 0, 0, 0);
            __builtin_amdgcn_s_setprio(0);
        }
    };

    // run over 64-k-tiles [ki0, ki1) of 128-row q-tile qt
    auto run = [&](int qt, int ki0, int ki1, bool diag) {
        int q0 = qt * 128 + w * 16;
        load_q(q0);
        reset_acc();
        int nseg = ki1 - ki0;
        issueK(0, ki0);
        short8 rva = loadV(ki0 * 64), rvb;
        int bk = 0;
        for (int ii = 0; ii < nseg; ++ii) {
            int ki = ki0 + ii, cv = ii & 1;
            bool pre = (ii + 1 < nseg);
            int bk1 = (bk == 2) ? 0 : bk + 1;
            if (pre) issueK(bk1, ki + 1);
            if (pre) asm volatile("s_waitcnt vmcnt(2)" ::: "memory");
            else     asm volatile("s_waitcnt vmcnt(0)" ::: "memory");
            __builtin_amdgcn_sched_barrier(0);
            if (cv == 0) {
                *(short8*)&Vt[0][vd][vch * 8] = rva;
                if (pre) rvb = loadV((ki + 1) * 64);
            } else {
                *(short8*)&Vt[1][vd][vch * 8] = rvb;
                if (pre) rva = loadV((ki + 1) * 64);
            }
            asm volatile("s_waitcnt lgkmcnt(0)" ::: "memory");
            __builtin_amdgcn_sched_barrier(0);
            __builtin_amdgcn_s_barrier();
            tile_compute(bk, cv, ki * 64, q0, diag && (ki >= 2 * qt));
            bk = bk1;
        }
        __builtin_amdgcn_s_barrier();   // protect LDS reuse across runs
    };

    if (e == 0) {
        run(qtA, 0, 2 * p + 2, true);
        {
            int q0 = qtA * 128 + w * 16;
#pragma unroll
            for (int j = 0; j < 4; ++j) {
                float i1 = 1.f / accl[0][j];
                float i2 = lam / accl[1][j];
                int qr = q0 + kq * 4 + j;
                __hip_bfloat16* orow = ob + ((long)(b * S_ + qr) * H_ + h) * 64;
#pragma unroll
                for (int dt = 0; dt < 4; ++dt) {
                    float val = acc[0][dt][j] * i1 - acc[1][dt][j] * i2;
                    orow[dt * 16 + r] = __float2bfloat16(val);
                }
            }
        }
        run(qtB, 0, 15 - 2 * p, false);             // k-prefix of qtB
    } else {
        run(qtB, 15 - 2 * p, 32 - 2 * p, true);     // k-suffix incl diagonal
    }

    // write packed partial: slot = (b*H+h)*8 + (qtB-8), half = e; dword = (m0,m1) bf16x2
    {
        long slot = (long)(b * H_ + h) * 8 + (qtB - 8);
        long base = (slot * 2 + e) * 8192L;
        int qloc = w * 16 + kq * 4;
#pragma unroll
        for (int dt = 0; dt < 4; ++dt)
#pragma unroll
            for (int j = 0; j < 4; ++j)
                part[base + (qloc + j) * 64 + dt * 16 + r] =
                    (unsigned)cvt_pk_bf16(acc[0][dt][j], acc[1][dt][j]);
        if (r == 0) {
#pragma unroll
            for (int m = 0; m < 2; ++m)
#pragma unroll
                for (int j = 0; j < 4; ++j)
                    lpart[((slot * 2 + e) * 2 + m) * 128 + qloc + j] = accl[m][j];
        }
    }
}

// ---------------- merge packed partials for qt128 in [8,16) (unchanged r14) ----------
__global__ __launch_bounds__(256) void attn_merge_kernel(const unsigned* __restrict__ part,
                                                         const float* __restrict__ lpart,
                                                         __hip_bfloat16* __restrict__ ob,
                                                         const float* __restrict__ lam_p) {
    long sid = blockIdx.x;
    int t8 = sid & 7;
    int h = (sid >> 3) & (H_ - 1);
    int b = (int)(sid >> 7);
    int qt = 8 + t8;
    float lam = lam_p[0];
    const unsigned* p0 = part + sid * 2 * 8192L;
    const unsigned* p1 = p0 + 8192;
    const float* l0 = lpart + sid * 512L;
    const float* l1 = l0 + 256;
    int tid = threadIdx.x;
#pragma unroll
    for (int i = 0; i < 32; ++i) {
        int idx = i * 256 + tid;
        int q = idx >> 6, d = idx & 63;
        unsigned u0 = p0[q * 64 + d], u1 = p1[q * 64 + d];
        float a1 = bf16lo(u0) + bf16lo(u1);
        float a2 = bf16hi(u0) + bf16hi(u1);
        float L1 = l0[q] + l1[q];
        float L2 = l0[128 + q] + l1[128 + q];
        float val = a1 / L1 - lam * (a2 / L2);
        ob[((long)(b * S_ + qt * 128 + q) * H_ + h) * 64 + d] = __float2bfloat16(val);
    }
}

// ---------------- launch ----------------
extern "C" void kernel_launch(void* const* d_in, const int* in_sizes, int n_in,
                              void* d_out, int out_size, void* d_ws, size_t ws_size,
                              hipStream_t stream) {
    const float* x     = (const float*)d_in[0];
    const float* freqs = (const float*)d_in[1];
    const float* wq    = (const float*)d_in[2];
    const float* wk    = (const float*)d_in[3];
    const float* wv    = (const float*)d_in[4];
    const float* wo    = (const float*)d_in[5];
    const float* qnw   = (const float*)d_in[6];
    const float* knw   = (const float*)d_in[7];
    const float* lam   = (const float*)d_in[8];
    float* out = (float*)d_out;

    const int T = B_ * S_;
    char* ws = (char*)d_ws;
    size_t off = 0;
    auto alloc = [&](size_t bytes) {
        void* p = ws + off;
        off += (bytes + 255) & ~(size_t)255;
        return p;
    };
    __hip_bfloat16* xb   = (__hip_bfloat16*)alloc((size_t)T * D_ * 2);
    __hip_bfloat16* wcat = (__hip_bfloat16*)alloc((size_t)NCAT * D_ * 2);
    __hip_bfloat16* wob  = (__hip_bfloat16*)alloc((size_t)D_ * D_ * 2);
    __hip_bfloat16* qb16 = (__hip_bfloat16*)alloc((size_t)T * 2 * H_ * HD_ * 2);
    __hip_bfloat16* kb16 = (__hip_bfloat16*)alloc((size_t)T * 2 * KV_ * HD_ * 2);
    __hip_bfloat16* vT   = (__hip_bfloat16*)alloc((size_t)B_ * KV_ * HD_ * S_ * 2);
    unsigned* part = (unsigned*)alloc((size_t)256 * 2 * 8192 * 4);
    float* lpart   = (float*)alloc((size_t)256 * 2 * 2 * 128 * 4);
    __hip_bfloat16* aob  = xb;   // xb dead after QKV GEMM; same size

    cvt5_kernel<<<dim3(2048, 5), 256, 0, stream>>>(
        x, wq, wk, wv, wo,
        xb, wcat, wcat + (size_t)2 * H_ * HD_ * D_,
        wcat + (size_t)(2 * H_ * HD_ + 2 * KV_ * HD_) * D_, wob,
        T * D_, 2 * H_ * HD_ * D_, 2 * KV_ * HD_ * D_, KV_ * HD_ * D_, D_ * D_);

    gemm_qkv_fused<<<dim3(NCAT / 128, T / 128), 256, 0, stream>>>(
        (const short*)xb, (const short*)wcat, qb16, kb16, vT,
        freqs, qnw, knw, T, NCAT, D_);

    attn_kernel<<<512, 512, 0, stream>>>(
        (const short*)qb16, (const short*)kb16, (const short*)vT, aob, part, lpart, lam);
    attn_merge_kernel<<<256, 256, 0, stream>>>(part, lpart, aob, lam);

    gemm_bt_lds<float><<<dim3(D_ / 128, T / 128), 256, 0, stream>>>(
        (const short*)aob, (const short*)wob, out, T, D_, D_);
}

// Round 16
// 159.708 us; speedup vs baseline: 1.3265x; 1.3265x over previous
//
#include <hip/hip_runtime.h>
#include <hip/hip_bf16.h>

#define B_ 2
#define S_ 2048
#define D_ 1024
#define H_ 16
#define KV_ 4
#define HD_ 64
#define G_ (H_ / KV_)
#define NCAT 2816          // 2*H*HD + 2*KV*HD + KV*HD
#define VOFF 2560          // col offset of V block in fused QKV output

typedef __attribute__((ext_vector_type(8))) short short8;
typedef __attribute__((ext_vector_type(4))) short short4v;
typedef __attribute__((ext_vector_type(2))) int int2v;
typedef __attribute__((ext_vector_type(4))) int int4v;
typedef __attribute__((ext_vector_type(4))) float floatx4;

using gvoid_p = const __attribute__((address_space(1))) void*;
using lvoid_p = __attribute__((address_space(3))) void*;

__device__ inline void gload_lds16(const short* g, short* l) {
    __builtin_amdgcn_global_load_lds((gvoid_p)(const void*)g, (lvoid_p)(void*)l, 16, 0, 0);
}

__device__ inline int cvt_pk_bf16(float lo, float hi) {
    int r;
    asm volatile("v_cvt_pk_bf16_f32 %0, %1, %2" : "=v"(r) : "v"(lo), "v"(hi));
    return r;
}

__device__ inline float bf16lo(unsigned u) {
    return __builtin_bit_cast(float, u << 16);
}
__device__ inline float bf16hi(unsigned u) {
    return __builtin_bit_cast(float, u & 0xffff0000u);
}

// ---------------- fused fp32 -> bf16 convert (5 segments, float4 vectorized) -------------
__global__ void cvt5_kernel(const float* s0, const float* s1, const float* s2,
                            const float* s3, const float* s4,
                            __hip_bfloat16* d0, __hip_bfloat16* d1, __hip_bfloat16* d2,
                            __hip_bfloat16* d3, __hip_bfloat16* d4,
                            int n0, int n1, int n2, int n3, int n4) {
    const float* s; __hip_bfloat16* d; int n;
    switch (blockIdx.y) {
        case 0: s = s0; d = d0; n = n0; break;
        case 1: s = s1; d = d1; n = n1; break;
        case 2: s = s2; d = d2; n = n2; break;
        case 3: s = s3; d = d3; n = n3; break;
        default: s = s4; d = d4; n = n4; break;
    }
    int nv = n >> 2;
    for (int i = blockIdx.x * blockDim.x + threadIdx.x; i < nv;
         i += gridDim.x * blockDim.x) {
        floatx4 v = ((const floatx4*)s)[i];
        short4v o;
#pragma unroll
        for (int e = 0; e < 4; ++e) {
            __hip_bfloat16 hh = __float2bfloat16(v[e]);
            o[e] = __builtin_bit_cast(short, hh);
        }
        ((short4v*)d)[i] = o;
    }
}

// ---------------- QKV GEMM with FUSED RMSNorm+RoPE epilogue ----------------
__global__ __launch_bounds__(256) void gemm_qkv_fused(const short* __restrict__ A,
                                                      const short* __restrict__ Bm,
                                                      __hip_bfloat16* __restrict__ qout,
                                                      __hip_bfloat16* __restrict__ kout,
                                                      __hip_bfloat16* __restrict__ vout,
                                                      const float* __restrict__ freqs,
                                                      const float* __restrict__ qnw,
                                                      const float* __restrict__ knw,
                                                      int M, int N, int K) {
    __shared__ __align__(16) short As[2][128 * 32];
    __shared__ __align__(16) short Bs[2][128 * 32];
    int tid = threadIdx.x;
    int wid = tid >> 6, lane = tid & 63;
    int wr = wid >> 1, wc = wid & 1;
    int r = lane & 15, kq = lane >> 4;

    int nwg = gridDim.x * gridDim.y;
    int orig = blockIdx.y * gridDim.x + blockIdx.x;
    int wg = (orig & 7) * (nwg >> 3) + (orig >> 3);
    int bx = wg % gridDim.x, by = wg / gridDim.x;

    long m0 = (long)by * 128;
    long n0 = (long)bx * 128;

    const short* gA0 = A + (m0 + (tid >> 2)) * (long)K + (tid & 3) * 8;
    const short* gA1 = A + (m0 + 64 + (tid >> 2)) * (long)K + (tid & 3) * 8;
    const short* gB0 = Bm + (n0 + (tid >> 2)) * (long)K + (tid & 3) * 8;
    const short* gB1 = Bm + (n0 + 64 + (tid >> 2)) * (long)K + (tid & 3) * 8;

    auto stage = [&](int buf, int k0) {
        gload_lds16(gA0 + k0, &As[buf][wid * 512]);
        gload_lds16(gA1 + k0, &As[buf][2048 + wid * 512]);
        gload_lds16(gB0 + k0, &Bs[buf][wid * 512]);
        gload_lds16(gB1 + k0, &Bs[buf][2048 + wid * 512]);
    };

    floatx4 acc[4][4];
#pragma unroll
    for (int i = 0; i < 4; ++i)
#pragma unroll
        for (int j = 0; j < 4; ++j) acc[i][j] = {0.f, 0.f, 0.f, 0.f};

    int nt = K >> 5;
    stage(0, 0);
    for (int t = 0; t < nt; ++t) {
        int cur = t & 1;
        __builtin_amdgcn_s_barrier();
        if (t + 1 < nt) {
            stage(cur ^ 1, (t + 1) << 5);
            asm volatile("s_waitcnt vmcnt(4)" ::: "memory");
        } else {
            asm volatile("s_waitcnt vmcnt(0)" ::: "memory");
        }
        __builtin_amdgcn_sched_barrier(0);
        __builtin_amdgcn_s_barrier();
        short8 a[4], b[4];
#pragma unroll
        for (int mi = 0; mi < 4; ++mi)
            a[mi] = *(const short8*)&As[cur][(wr * 64 + mi * 16 + r) * 32 + kq * 8];
#pragma unroll
        for (int ni = 0; ni < 4; ++ni)
            b[ni] = *(const short8*)&Bs[cur][(wc * 64 + ni * 16 + r) * 32 + kq * 8];
#pragma unroll
        for (int mi = 0; mi < 4; ++mi)
#pragma unroll
            for (int ni = 0; ni < 4; ++ni)
                acc[mi][ni] = __builtin_amdgcn_mfma_f32_16x16x32_bf16(
                    a[mi], b[ni], acc[mi][ni], 0, 0, 0);
    }

    // ---------- fused epilogue ----------
    int col_l = lane & 15;
    int gbase = (int)n0 + wc * 64;
    int par = col_l & 1;
    if (gbase < VOFF) {
        const float* wnorm = (gbase < 2048) ? qnw : knw;
        float wv4[4];
        int fo[4];
#pragma unroll
        for (int ni = 0; ni < 4; ++ni) {
            wv4[ni] = wnorm[ni * 16 + col_l];
            fo[ni] = ni * 16 + (col_l >> 1) * 2;
        }
        __hip_bfloat16* outp;
        long tstride;
        int cbase;
        if (gbase < 2048) { outp = qout; tstride = 2048; cbase = gbase; }
        else              { outp = kout; tstride = 512;  cbase = gbase - 2048; }
#pragma unroll
        for (int mi = 0; mi < 4; ++mi) {
#pragma unroll
            for (int j = 0; j < 4; ++j) {
                int t = (int)m0 + wr * 64 + mi * 16 + kq * 4 + j;
                float ss = 0.f;
#pragma unroll
                for (int ni = 0; ni < 4; ++ni)
                    ss = fmaf(acc[mi][ni][j], acc[mi][ni][j], ss);
                ss += __shfl_xor(ss, 1); ss += __shfl_xor(ss, 2);
                ss += __shfl_xor(ss, 4); ss += __shfl_xor(ss, 8);
                float rr = rsqrtf(ss * (1.f / 64.f) + 1e-6f);
                const float* fb = freqs + (long)(t & (S_ - 1)) * 64;
                __hip_bfloat16* orow = outp + (long)t * tstride + cbase;
#pragma unroll
                for (int ni = 0; ni < 4; ++ni) {
                    float xv = acc[mi][ni][j] * rr * wv4[ni];
                    float pp = __shfl_xor(xv, 1);
                    float cc = fb[fo[ni]], sn = fb[fo[ni] + 1];
                    float y = par ? fmaf(pp, sn, xv * cc) : fmaf(xv, cc, -(pp * sn));
                    orow[ni * 16 + col_l] = __float2bfloat16(y);
                }
            }
        }
    } else {
        int kvv = (gbase - VOFF) >> 6;
#pragma unroll
        for (int mi = 0; mi < 4; ++mi) {
#pragma unroll
            for (int j = 0; j < 4; ++j) {
                int t = (int)m0 + wr * 64 + mi * 16 + kq * 4 + j;
                int bb = t >> 11, st = t & (S_ - 1);
                __hip_bfloat16* vcol = vout + ((long)(bb * KV_ + kvv) * 64) * S_ + st;
#pragma unroll
                for (int ni = 0; ni < 4; ++ni)
                    vcol[(long)(ni * 16 + col_l) * S_] = __float2bfloat16(acc[mi][ni][j]);
            }
        }
    }
}

// ---------------- NT GEMM (out-projection) ----------
template <typename OutT>
__global__ __launch_bounds__(256) void gemm_bt_lds(const short* __restrict__ A,
                                                   const short* __restrict__ Bm,
                                                   OutT* __restrict__ C,
                                                   int M, int N, int K) {
    __shared__ __align__(16) short As[2][128 * 32];
    __shared__ __align__(16) short Bs[2][128 * 32];
    int tid = threadIdx.x;
    int wid = tid >> 6, lane = tid & 63;
    int wr = wid >> 1, wc = wid & 1;
    int r = lane & 15, kq = lane >> 4;

    int nwg = gridDim.x * gridDim.y;
    int orig = blockIdx.y * gridDim.x + blockIdx.x;
    int wg = (orig & 7) * (nwg >> 3) + (orig >> 3);
    int bx = wg % gridDim.x, by = wg / gridDim.x;

    long m0 = (long)by * 128;
    long n0 = (long)bx * 128;

    const short* gA0 = A + (m0 + (tid >> 2)) * (long)K + (tid & 3) * 8;
    const short* gA1 = A + (m0 + 64 + (tid >> 2)) * (long)K + (tid & 3) * 8;
    const short* gB0 = Bm + (n0 + (tid >> 2)) * (long)K + (tid & 3) * 8;
    const short* gB1 = Bm + (n0 + 64 + (tid >> 2)) * (long)K + (tid & 3) * 8;

    auto stage = [&](int buf, int k0) {
        gload_lds16(gA0 + k0, &As[buf][wid * 512]);
        gload_lds16(gA1 + k0, &As[buf][2048 + wid * 512]);
        gload_lds16(gB0 + k0, &Bs[buf][wid * 512]);
        gload_lds16(gB1 + k0, &Bs[buf][2048 + wid * 512]);
    };

    floatx4 acc[4][4];
#pragma unroll
    for (int i = 0; i < 4; ++i)
#pragma unroll
        for (int j = 0; j < 4; ++j) acc[i][j] = {0.f, 0.f, 0.f, 0.f};

    int nt = K >> 5;
    stage(0, 0);
    for (int t = 0; t < nt; ++t) {
        int cur = t & 1;
        __builtin_amdgcn_s_barrier();
        if (t + 1 < nt) {
            stage(cur ^ 1, (t + 1) << 5);
            asm volatile("s_waitcnt vmcnt(4)" ::: "memory");
        } else {
            asm volatile("s_waitcnt vmcnt(0)" ::: "memory");
        }
        __builtin_amdgcn_sched_barrier(0);
        __builtin_amdgcn_s_barrier();
        short8 a[4], b[4];
#pragma unroll
        for (int mi = 0; mi < 4; ++mi)
            a[mi] = *(const short8*)&As[cur][(wr * 64 + mi * 16 + r) * 32 + kq * 8];
#pragma unroll
        for (int ni = 0; ni < 4; ++ni)
            b[ni] = *(const short8*)&Bs[cur][(wc * 64 + ni * 16 + r) * 32 + kq * 8];
#pragma unroll
        for (int mi = 0; mi < 4; ++mi)
#pragma unroll
            for (int ni = 0; ni < 4; ++ni)
                acc[mi][ni] = __builtin_amdgcn_mfma_f32_16x16x32_bf16(
                    a[mi], b[ni], acc[mi][ni], 0, 0, 0);
    }
    int col_l = lane & 15, row_l = (lane >> 4) * 4;
#pragma unroll
    for (int mi = 0; mi < 4; ++mi)
#pragma unroll
        for (int ni = 0; ni < 4; ++ni) {
            long col = n0 + wc * 64 + ni * 16 + col_l;
            long row0 = m0 + wr * 64 + mi * 16 + row_l;
#pragma unroll
            for (int j = 0; j < 4; ++j) {
                float v = acc[mi][ni][j];
                if constexpr (__is_same(OutT, float))
                    C[(row0 + j) * N + col] = v;
                else
                    C[(row0 + j) * N + col] = __float2bfloat16(v);
            }
        }
}

// ---------------- differential causal attention: 512-thread blocks, QBLK=128 ----------
// (r14-proven: KVBLK=32, 8 waves x 16 q-rows, K triple-buffer gload_lds + source-XOR
// swizzle, V reg-staged by waves 0-3 into Vt[2][64][40], vmcnt(1) steady, one barrier
// per tile, PV-x32 sigma pairing, ones8 row-sums, packed bf16x2 partials.)
__global__ __launch_bounds__(512, 4) void attn_kernel(const short* __restrict__ qb,
                                                      const short* __restrict__ kbuf,
                                                      const short* __restrict__ vtb,
                                                      __hip_bfloat16* __restrict__ ob,
                                                      unsigned* __restrict__ part,
                                                      float* __restrict__ lpart,
                                                      const float* __restrict__ lam_p) {
    __shared__ __align__(16) short Ks[3][32][128];
    __shared__ __align__(16) short Vt[2][64][40];

    int tid = threadIdx.x, w = tid >> 6, lane = tid & 63;
    int raw = (int)blockIdx.x;
    int xcd = raw & 7;
    int kv = xcd & 3, b = xcd >> 2;
    int i5 = raw >> 3;                  // [0,64)
    int x = i5 & 15, hh = i5 >> 4;      // x: pair+e, hh: head-in-group
    int h = kv * G_ + hh;
    int p = x >> 1, e = x & 1;
    int qtA = p, qtB = 15 - p;          // 128-row q-tiles
    int r = lane & 15, kq = lane >> 4;
    bool w4 = (w < 4);
    float lam = lam_p[0];

    floatx4 acc[2][4];
    floatx4 accl[2];
    short8 qa[2][2];

    const short* vbase = vtb + (long)(b * KV_ + kv) * 64 * S_;
    const float c1 = 0.18033688f, nc4 = -3.7570e-7f, zoff = -17.3123405f;
    const short one_bf = (short)0x3F80;
    short8 ones8 = {one_bf, one_bf, one_bf, one_bf, one_bf, one_bf, one_bf, one_bf};

    int krow0 = tid >> 4, kcs0 = ((tid & 15) ^ (krow0 & 7)) * 8;
    const short* kgb = kbuf + ((long)b * S_ * KV_ + kv) * 128;
    int vd = (tid >> 2) & 63, vch = tid & 3;   // V chunk (waves 0-3 only)

    auto issueK = [&](int buf, int ki) {
        long rb = (long)(ki * 32) * (KV_ * 128);
        gload_lds16(kgb + rb + (long)krow0 * (KV_ * 128) + kcs0, &Ks[buf][0][0] + w * 512);
    };
    auto loadV = [&](int kb) {
        return *(const short8*)(vbase + (long)vd * S_ + kb + vch * 8);
    };

    auto reset_acc = [&]() {
#pragma unroll
        for (int m = 0; m < 2; ++m) {
            accl[m] = {0.f, 0.f, 0.f, 0.f};
#pragma unroll
            for (int dt = 0; dt < 4; ++dt) acc[m][dt] = {0.f, 0.f, 0.f, 0.f};
        }
    };
    auto load_q = [&](int q0) {
        const short* qrow = qb + ((long)(b * S_ + q0 + r) * H_ + h) * 128;
        qa[0][0] = *(const short8*)(qrow + kq * 8);
        qa[0][1] = *(const short8*)(qrow + 32 + kq * 8);
        qa[1][0] = *(const short8*)(qrow + 64 + kq * 8);
        qa[1][1] = *(const short8*)(qrow + 96 + kq * 8);
    };

    auto tile_compute = [&](int bk, int cv, int kb, int q0, bool domask) {
        int rel = q0 + r - kb;
        short8 vb[4];
#pragma unroll
        for (int dt = 0; dt < 4; ++dt) {
            const short* vrow = &Vt[cv][dt * 16 + r][0];
            int2v lo = *(const int2v*)(vrow + 4 * kq);
            int2v hi = *(const int2v*)(vrow + 16 + 4 * kq);
            vb[dt] = __builtin_bit_cast(short8, int4v{lo[0], lo[1], hi[0], hi[1]});
        }
#pragma unroll
        for (int m = 0; m < 2; ++m) {
            floatx4 sacc[2];
            __builtin_amdgcn_s_setprio(1);
#pragma unroll
            for (int nt = 0; nt < 2; ++nt) {
                sacc[nt] = {0.f, 0.f, 0.f, 0.f};
                const short* row = &Ks[bk][nt * 16 + r][0];
                short8 a0 = *(const short8*)(row + (((m * 8) + kq) ^ (r & 7)) * 8);
                short8 a1 = *(const short8*)(row + (((m * 8) + 4 + kq) ^ (r & 7)) * 8);
                sacc[nt] = __builtin_amdgcn_mfma_f32_16x16x32_bf16(a0, qa[m][0], sacc[nt], 0, 0, 0);
                sacc[nt] = __builtin_amdgcn_mfma_f32_16x16x32_bf16(a1, qa[m][1], sacc[nt], 0, 0, 0);
            }
            __builtin_amdgcn_s_setprio(0);
            float pv[2][4];
#pragma unroll
            for (int nt = 0; nt < 2; ++nt)
#pragma unroll
                for (int j = 0; j < 4; ++j) {
                    float rawv = sacc[nt][j];
                    float r2 = rawv * rawv;
                    float z = fmaf(rawv, fmaf(r2, nc4, c1), zoff);
                    pv[nt][j] = __builtin_amdgcn_exp2f(z);
                }
            if (domask) {
#pragma unroll
                for (int nt = 0; nt < 2; ++nt)
#pragma unroll
                    for (int j = 0; j < 4; ++j)
                        if (nt * 16 + kq * 4 + j > rel) pv[nt][j] = 0.f;
            }
            int d0 = cvt_pk_bf16(pv[0][0], pv[0][1]);
            int d1 = cvt_pk_bf16(pv[0][2], pv[0][3]);
            int d2 = cvt_pk_bf16(pv[1][0], pv[1][1]);
            int d3 = cvt_pk_bf16(pv[1][2], pv[1][3]);
            short8 pa8 = __builtin_bit_cast(short8, int4v{d0, d1, d2, d3});
            __builtin_amdgcn_s_setprio(1);
#pragma unroll
            for (int dt = 0; dt < 4; ++dt)
                acc[m][dt] = __builtin_amdgcn_mfma_f32_16x16x32_bf16(
                    pa8, vb[dt], acc[m][dt], 0, 0, 0);
            accl[m] = __builtin_amdgcn_mfma_f32_16x16x32_bf16(pa8, ones8, accl[m], 0, 0, 0);
            __builtin_amdgcn_s_setprio(0);
        }
    };

    // run over 32-k-tiles [ki0, ki1) of 128-row q-tile qt
    auto run = [&](int qt, int ki0, int ki1, bool diag) {
        int q0 = qt * 128 + w * 16;
        load_q(q0);
        reset_acc();
        int nseg = ki1 - ki0;
        issueK(0, ki0);
        short8 rva = {}, rvb = {};
        if (w4) rva = loadV(ki0 * 32);
        int bk = 0;
        for (int ii = 0; ii < nseg; ++ii) {
            int ki = ki0 + ii, cv = ii & 1;
            bool pre = (ii + 1 < nseg);
            int bk1 = (bk == 2) ? 0 : bk + 1;
            if (pre) issueK(bk1, ki + 1);
            if (pre) asm volatile("s_waitcnt vmcnt(1)" ::: "memory");
            else     asm volatile("s_waitcnt vmcnt(0)" ::: "memory");
            __builtin_amdgcn_sched_barrier(0);
            if (cv == 0) {
                if (w4) {
                    *(short8*)&Vt[0][vd][vch * 8] = rva;
                    if (pre) rvb = loadV((ki + 1) * 32);
                }
            } else {
                if (w4) {
                    *(short8*)&Vt[1][vd][vch * 8] = rvb;
                    if (pre) rva = loadV((ki + 1) * 32);
                }
            }
            asm volatile("s_waitcnt lgkmcnt(0)" ::: "memory");
            __builtin_amdgcn_sched_barrier(0);
            __builtin_amdgcn_s_barrier();
            tile_compute(bk, cv, ki * 32, q0, diag && (ki >= 4 * qt));
            bk = bk1;
        }
        __builtin_amdgcn_s_barrier();   // protect LDS reuse across runs
    };

    if (e == 0) {
        run(qtA, 0, 4 * qtA + 4, true);
        {
            int q0 = qtA * 128 + w * 16;
#pragma unroll
            for (int j = 0; j < 4; ++j) {
                float i1 = 1.f / accl[0][j];
                float i2 = lam / accl[1][j];
                int qr = q0 + kq * 4 + j;
                __hip_bfloat16* orow = ob + ((long)(b * S_ + qr) * H_ + h) * 64;
#pragma unroll
                for (int dt = 0; dt < 4; ++dt) {
                    float val = acc[0][dt][j] * i1 - acc[1][dt][j] * i2;
                    orow[dt * 16 + r] = __float2bfloat16(val);
                }
            }
        }
        run(qtB, 0, 30 - 4 * p, false);             // k-prefix of qtB
    } else {
        run(qtB, 30 - 4 * p, 64 - 4 * p, true);     // k-suffix incl diagonal
    }

    // write packed partial: slot = (b*H+h)*8 + (qtB-8), half = e; dword = (m0,m1) bf16x2
    {
        long slot = (long)(b * H_ + h) * 8 + (qtB - 8);
        long base = (slot * 2 + e) * 8192L;
        int qloc = w * 16 + kq * 4;
#pragma unroll
        for (int dt = 0; dt < 4; ++dt)
#pragma unroll
            for (int j = 0; j < 4; ++j)
                part[base + (qloc + j) * 64 + dt * 16 + r] =
                    (unsigned)cvt_pk_bf16(acc[0][dt][j], acc[1][dt][j]);
        if (r == 0) {
#pragma unroll
            for (int m = 0; m < 2; ++m)
#pragma unroll
                for (int j = 0; j < 4; ++j)
                    lpart[((slot * 2 + e) * 2 + m) * 128 + qloc + j] = accl[m][j];
        }
    }
}

// ---------------- merge packed partials for qt128 in [8,16) ----------
__global__ __launch_bounds__(256) void attn_merge_kernel(const unsigned* __restrict__ part,
                                                         const float* __restrict__ lpart,
                                                         __hip_bfloat16* __restrict__ ob,
                                                         const float* __restrict__ lam_p) {
    long sid = blockIdx.x;               // (b*H+h)*8 + (qt-8), 256 slots
    int t8 = sid & 7;
    int h = (sid >> 3) & (H_ - 1);
    int b = (int)(sid >> 7);
    int qt = 8 + t8;
    float lam = lam_p[0];
    const unsigned* p0 = part + sid * 2 * 8192L;
    const unsigned* p1 = p0 + 8192;
    const float* l0 = lpart + sid * 512L;    // e=0: m0 at +0, m1 at +128
    const float* l1 = l0 + 256;              // e=1
    int tid = threadIdx.x;
#pragma unroll
    for (int i = 0; i < 32; ++i) {
        int idx = i * 256 + tid;
        int q = idx >> 6, d = idx & 63;
        unsigned u0 = p0[q * 64 + d], u1 = p1[q * 64 + d];
        float a1 = bf16lo(u0) + bf16lo(u1);
        float a2 = bf16hi(u0) + bf16hi(u1);
        float L1 = l0[q] + l1[q];
        float L2 = l0[128 + q] + l1[128 + q];
        float val = a1 / L1 - lam * (a2 / L2);
        ob[((long)(b * S_ + qt * 128 + q) * H_ + h) * 64 + d] = __float2bfloat16(val);
    }
}

// ---------------- launch ----------------
extern "C" void kernel_launch(void* const* d_in, const int* in_sizes, int n_in,
                              void* d_out, int out_size, void* d_ws, size_t ws_size,
                              hipStream_t stream) {
    const float* x     = (const float*)d_in[0];
    const float* freqs = (const float*)d_in[1];
    const float* wq    = (const float*)d_in[2];
    const float* wk    = (const float*)d_in[3];
    const float* wv    = (const float*)d_in[4];
    const float* wo    = (const float*)d_in[5];
    const float* qnw   = (const float*)d_in[6];
    const float* knw   = (const float*)d_in[7];
    const float* lam   = (const float*)d_in[8];
    float* out = (float*)d_out;

    const int T = B_ * S_;
    char* ws = (char*)d_ws;
    size_t off = 0;
    auto alloc = [&](size_t bytes) {
        void* p = ws + off;
        off += (bytes + 255) & ~(size_t)255;
        return p;
    };
    __hip_bfloat16* xb   = (__hip_bfloat16*)alloc((size_t)T * D_ * 2);
    __hip_bfloat16* wcat = (__hip_bfloat16*)alloc((size_t)NCAT * D_ * 2);
    __hip_bfloat16* wob  = (__hip_bfloat16*)alloc((size_t)D_ * D_ * 2);
    __hip_bfloat16* qb16 = (__hip_bfloat16*)alloc((size_t)T * 2 * H_ * HD_ * 2);
    __hip_bfloat16* kb16 = (__hip_bfloat16*)alloc((size_t)T * 2 * KV_ * HD_ * 2);
    __hip_bfloat16* vT   = (__hip_bfloat16*)alloc((size_t)B_ * KV_ * HD_ * S_ * 2);
    unsigned* part = (unsigned*)alloc((size_t)256 * 2 * 8192 * 4);
    float* lpart   = (float*)alloc((size_t)256 * 2 * 2 * 128 * 4);
    __hip_bfloat16* aob  = xb;   // xb dead after QKV GEMM; same size

    // fused cvt: x, wq, wk, wv, wo (wcat segments are contiguous)
    cvt5_kernel<<<dim3(2048, 5), 256, 0, stream>>>(
        x, wq, wk, wv, wo,
        xb, wcat, wcat + (size_t)2 * H_ * HD_ * D_,
        wcat + (size_t)(2 * H_ * HD_ + 2 * KV_ * HD_) * D_, wob,
        T * D_, 2 * H_ * HD_ * D_, 2 * KV_ * HD_ * D_, KV_ * HD_ * D_, D_ * D_);

    // fused QKV projection + RMSNorm + RoPE + V-transpose
    gemm_qkv_fused<<<dim3(NCAT / 128, T / 128), 256, 0, stream>>>(
        (const short*)xb, (const short*)wcat, qb16, kb16, vT,
        freqs, qnw, knw, T, NCAT, D_);

    // differential causal attention + merge
    attn_kernel<<<512, 512, 0, stream>>>(
        (const short*)qb16, (const short*)kb16, (const short*)vT, aob, part, lpart, lam);
    attn_merge_kernel<<<256, 256, 0, stream>>>(part, lpart, aob, lam);

    // output projection -> f32
    gemm_bt_lds<float><<<dim3(D_ / 128, T / 128), 256, 0, stream>>>(
        (const short*)aob, (const short*)wob, out, T, D_, D_);
}

// Round 17
// 156.554 us; speedup vs baseline: 1.3532x; 1.0201x over previous
//
#include <hip/hip_runtime.h>
#include <hip/hip_bf16.h>

#define B_ 2
#define S_ 2048
#define D_ 1024
#define H_ 16
#define KV_ 4
#define HD_ 64
#define G_ (H_ / KV_)
#define NCAT 2816          // 2*H*HD + 2*KV*HD + KV*HD
#define VOFF 2560          // col offset of V block in fused QKV output

typedef __attribute__((ext_vector_type(8))) short short8;
typedef __attribute__((ext_vector_type(4))) short short4v;
typedef __attribute__((ext_vector_type(2))) int int2v;
typedef __attribute__((ext_vector_type(4))) int int4v;
typedef __attribute__((ext_vector_type(4))) float floatx4;

using gvoid_p = const __attribute__((address_space(1))) void*;
using lvoid_p = __attribute__((address_space(3))) void*;

__device__ inline void gload_lds16(const short* g, short* l) {
    __builtin_amdgcn_global_load_lds((gvoid_p)(const void*)g, (lvoid_p)(void*)l, 16, 0, 0);
}

__device__ inline int cvt_pk_bf16(float lo, float hi) {
    int r;
    asm volatile("v_cvt_pk_bf16_f32 %0, %1, %2" : "=v"(r) : "v"(lo), "v"(hi));
    return r;
}

__device__ inline float bf16lo(unsigned u) {
    return __builtin_bit_cast(float, u << 16);
}
__device__ inline float bf16hi(unsigned u) {
    return __builtin_bit_cast(float, u & 0xffff0000u);
}

// ---------------- fused fp32 -> bf16 convert (5 segments, float4 vectorized) -------------
__global__ void cvt5_kernel(const float* s0, const float* s1, const float* s2,
                            const float* s3, const float* s4,
                            __hip_bfloat16* d0, __hip_bfloat16* d1, __hip_bfloat16* d2,
                            __hip_bfloat16* d3, __hip_bfloat16* d4,
                            int n0, int n1, int n2, int n3, int n4) {
    const float* s; __hip_bfloat16* d; int n;
    switch (blockIdx.y) {
        case 0: s = s0; d = d0; n = n0; break;
        case 1: s = s1; d = d1; n = n1; break;
        case 2: s = s2; d = d2; n = n2; break;
        case 3: s = s3; d = d3; n = n3; break;
        default: s = s4; d = d4; n = n4; break;
    }
    int nv = n >> 2;
    for (int i = blockIdx.x * blockDim.x + threadIdx.x; i < nv;
         i += gridDim.x * blockDim.x) {
        floatx4 v = ((const floatx4*)s)[i];
        short4v o;
#pragma unroll
        for (int e = 0; e < 4; ++e) {
            __hip_bfloat16 hh = __float2bfloat16(v[e]);
            o[e] = __builtin_bit_cast(short, hh);
        }
        ((short4v*)d)[i] = o;
    }
}

// ---------------- QKV GEMM with FUSED RMSNorm+RoPE epilogue ----------------
__global__ __launch_bounds__(256) void gemm_qkv_fused(const short* __restrict__ A,
                                                      const short* __restrict__ Bm,
                                                      __hip_bfloat16* __restrict__ qout,
                                                      __hip_bfloat16* __restrict__ kout,
                                                      __hip_bfloat16* __restrict__ vout,
                                                      const float* __restrict__ freqs,
                                                      const float* __restrict__ qnw,
                                                      const float* __restrict__ knw,
                                                      int M, int N, int K) {
    __shared__ __align__(16) short As[2][128 * 32];
    __shared__ __align__(16) short Bs[2][128 * 32];
    int tid = threadIdx.x;
    int wid = tid >> 6, lane = tid & 63;
    int wr = wid >> 1, wc = wid & 1;
    int r = lane & 15, kq = lane >> 4;

    int nwg = gridDim.x * gridDim.y;
    int orig = blockIdx.y * gridDim.x + blockIdx.x;
    int wg = (orig & 7) * (nwg >> 3) + (orig >> 3);
    int bx = wg % gridDim.x, by = wg / gridDim.x;

    long m0 = (long)by * 128;
    long n0 = (long)bx * 128;

    const short* gA0 = A + (m0 + (tid >> 2)) * (long)K + (tid & 3) * 8;
    const short* gA1 = A + (m0 + 64 + (tid >> 2)) * (long)K + (tid & 3) * 8;
    const short* gB0 = Bm + (n0 + (tid >> 2)) * (long)K + (tid & 3) * 8;
    const short* gB1 = Bm + (n0 + 64 + (tid >> 2)) * (long)K + (tid & 3) * 8;

    auto stage = [&](int buf, int k0) {
        gload_lds16(gA0 + k0, &As[buf][wid * 512]);
        gload_lds16(gA1 + k0, &As[buf][2048 + wid * 512]);
        gload_lds16(gB0 + k0, &Bs[buf][wid * 512]);
        gload_lds16(gB1 + k0, &Bs[buf][2048 + wid * 512]);
    };

    floatx4 acc[4][4];
#pragma unroll
    for (int i = 0; i < 4; ++i)
#pragma unroll
        for (int j = 0; j < 4; ++j) acc[i][j] = {0.f, 0.f, 0.f, 0.f};

    int nt = K >> 5;
    stage(0, 0);
    for (int t = 0; t < nt; ++t) {
        int cur = t & 1;
        __builtin_amdgcn_s_barrier();
        if (t + 1 < nt) {
            stage(cur ^ 1, (t + 1) << 5);
            asm volatile("s_waitcnt vmcnt(4)" ::: "memory");
        } else {
            asm volatile("s_waitcnt vmcnt(0)" ::: "memory");
        }
        __builtin_amdgcn_sched_barrier(0);
        __builtin_amdgcn_s_barrier();
        short8 a[4], b[4];
#pragma unroll
        for (int mi = 0; mi < 4; ++mi)
            a[mi] = *(const short8*)&As[cur][(wr * 64 + mi * 16 + r) * 32 + kq * 8];
#pragma unroll
        for (int ni = 0; ni < 4; ++ni)
            b[ni] = *(const short8*)&Bs[cur][(wc * 64 + ni * 16 + r) * 32 + kq * 8];
#pragma unroll
        for (int mi = 0; mi < 4; ++mi)
#pragma unroll
            for (int ni = 0; ni < 4; ++ni)
                acc[mi][ni] = __builtin_amdgcn_mfma_f32_16x16x32_bf16(
                    a[mi], b[ni], acc[mi][ni], 0, 0, 0);
    }

    // ---------- fused epilogue ----------
    int col_l = lane & 15;
    int gbase = (int)n0 + wc * 64;
    int par = col_l & 1;
    if (gbase < VOFF) {
        const float* wnorm = (gbase < 2048) ? qnw : knw;
        float wv4[4];
        int fo[4];
#pragma unroll
        for (int ni = 0; ni < 4; ++ni) {
            wv4[ni] = wnorm[ni * 16 + col_l];
            fo[ni] = ni * 16 + (col_l >> 1) * 2;
        }
        __hip_bfloat16* outp;
        long tstride;
        int cbase;
        if (gbase < 2048) { outp = qout; tstride = 2048; cbase = gbase; }
        else              { outp = kout; tstride = 512;  cbase = gbase - 2048; }
#pragma unroll
        for (int mi = 0; mi < 4; ++mi) {
#pragma unroll
            for (int j = 0; j < 4; ++j) {
                int t = (int)m0 + wr * 64 + mi * 16 + kq * 4 + j;
                float ss = 0.f;
#pragma unroll
                for (int ni = 0; ni < 4; ++ni)
                    ss = fmaf(acc[mi][ni][j], acc[mi][ni][j], ss);
                ss += __shfl_xor(ss, 1); ss += __shfl_xor(ss, 2);
                ss += __shfl_xor(ss, 4); ss += __shfl_xor(ss, 8);
                float rr = rsqrtf(ss * (1.f / 64.f) + 1e-6f);
                const float* fb = freqs + (long)(t & (S_ - 1)) * 64;
                __hip_bfloat16* orow = outp + (long)t * tstride + cbase;
#pragma unroll
                for (int ni = 0; ni < 4; ++ni) {
                    float xv = acc[mi][ni][j] * rr * wv4[ni];
                    float pp = __shfl_xor(xv, 1);
                    float cc = fb[fo[ni]], sn = fb[fo[ni] + 1];
                    float y = par ? fmaf(pp, sn, xv * cc) : fmaf(xv, cc, -(pp * sn));
                    orow[ni * 16 + col_l] = __float2bfloat16(y);
                }
            }
        }
    } else {
        int kvv = (gbase - VOFF) >> 6;
#pragma unroll
        for (int mi = 0; mi < 4; ++mi) {
#pragma unroll
            for (int j = 0; j < 4; ++j) {
                int t = (int)m0 + wr * 64 + mi * 16 + kq * 4 + j;
                int bb = t >> 11, st = t & (S_ - 1);
                __hip_bfloat16* vcol = vout + ((long)(bb * KV_ + kvv) * 64) * S_ + st;
#pragma unroll
                for (int ni = 0; ni < 4; ++ni)
                    vcol[(long)(ni * 16 + col_l) * S_] = __float2bfloat16(acc[mi][ni][j]);
            }
        }
    }
}

// ---------------- NT GEMM (out-projection) ----------
template <typename OutT>
__global__ __launch_bounds__(256) void gemm_bt_lds(const short* __restrict__ A,
                                                   const short* __restrict__ Bm,
                                                   OutT* __restrict__ C,
                                                   int M, int N, int K) {
    __shared__ __align__(16) short As[2][128 * 32];
    __shared__ __align__(16) short Bs[2][128 * 32];
    int tid = threadIdx.x;
    int wid = tid >> 6, lane = tid & 63;
    int wr = wid >> 1, wc = wid & 1;
    int r = lane & 15, kq = lane >> 4;

    int nwg = gridDim.x * gridDim.y;
    int orig = blockIdx.y * gridDim.x + blockIdx.x;
    int wg = (orig & 7) * (nwg >> 3) + (orig >> 3);
    int bx = wg % gridDim.x, by = wg / gridDim.x;

    long m0 = (long)by * 128;
    long n0 = (long)bx * 128;

    const short* gA0 = A + (m0 + (tid >> 2)) * (long)K + (tid & 3) * 8;
    const short* gA1 = A + (m0 + 64 + (tid >> 2)) * (long)K + (tid & 3) * 8;
    const short* gB0 = Bm + (n0 + (tid >> 2)) * (long)K + (tid & 3) * 8;
    const short* gB1 = Bm + (n0 + 64 + (tid >> 2)) * (long)K + (tid & 3) * 8;

    auto stage = [&](int buf, int k0) {
        gload_lds16(gA0 + k0, &As[buf][wid * 512]);
        gload_lds16(gA1 + k0, &As[buf][2048 + wid * 512]);
        gload_lds16(gB0 + k0, &Bs[buf][wid * 512]);
        gload_lds16(gB1 + k0, &Bs[buf][2048 + wid * 512]);
    };

    floatx4 acc[4][4];
#pragma unroll
    for (int i = 0; i < 4; ++i)
#pragma unroll
        for (int j = 0; j < 4; ++j) acc[i][j] = {0.f, 0.f, 0.f, 0.f};

    int nt = K >> 5;
    stage(0, 0);
    for (int t = 0; t < nt; ++t) {
        int cur = t & 1;
        __builtin_amdgcn_s_barrier();
        if (t + 1 < nt) {
            stage(cur ^ 1, (t + 1) << 5);
            asm volatile("s_waitcnt vmcnt(4)" ::: "memory");
        } else {
            asm volatile("s_waitcnt vmcnt(0)" ::: "memory");
        }
        __builtin_amdgcn_sched_barrier(0);
        __builtin_amdgcn_s_barrier();
        short8 a[4], b[4];
#pragma unroll
        for (int mi = 0; mi < 4; ++mi)
            a[mi] = *(const short8*)&As[cur][(wr * 64 + mi * 16 + r) * 32 + kq * 8];
#pragma unroll
        for (int ni = 0; ni < 4; ++ni)
            b[ni] = *(const short8*)&Bs[cur][(wc * 64 + ni * 16 + r) * 32 + kq * 8];
#pragma unroll
        for (int mi = 0; mi < 4; ++mi)
#pragma unroll
            for (int ni = 0; ni < 4; ++ni)
                acc[mi][ni] = __builtin_amdgcn_mfma_f32_16x16x32_bf16(
                    a[mi], b[ni], acc[mi][ni], 0, 0, 0);
    }
    int col_l = lane & 15, row_l = (lane >> 4) * 4;
#pragma unroll
    for (int mi = 0; mi < 4; ++mi)
#pragma unroll
        for (int ni = 0; ni < 4; ++ni) {
            long col = n0 + wc * 64 + ni * 16 + col_l;
            long row0 = m0 + wr * 64 + mi * 16 + row_l;
#pragma unroll
            for (int j = 0; j < 4; ++j) {
                float v = acc[mi][ni][j];
                if constexpr (__is_same(OutT, float))
                    C[(row0 + j) * N + col] = v;
                else
                    C[(row0 + j) * N + col] = __float2bfloat16(v);
            }
        }
}

// ---------------- differential causal attention: paired-tile loop ----------
// r16 base (QBLK=128, KVBLK=32, 8 waves, PV-x32 sigma, ones8, packed partials) with
// TWO tiles per barrier: K 4-deep buffer (tile t -> buf t&3), V 4-deep (pair p ->
// bufs {2(p&1), 2(p&1)+1}; waves 0-3 stage even tile, waves 4-7 odd tile, one rva
// reg each). DMAs/loads for pair p+1 issued AFTER barrier(p) -> target buffers were
// last read in compute(p-1), which precedes barrier(p) for every wave (race-free by
// construction). vmcnt(0) drains DMAs issued ~2 tiles earlier (hidden). All nseg even.
__global__ __launch_bounds__(512, 4) void attn_kernel(const short* __restrict__ qb,
                                                      const short* __restrict__ kbuf,
                                                      const short* __restrict__ vtb,
                                                      __hip_bfloat16* __restrict__ ob,
                                                      unsigned* __restrict__ part,
                                                      float* __restrict__ lpart,
                                                      const float* __restrict__ lam_p) {
    __shared__ __align__(16) short Ks[4][32][128];
    __shared__ __align__(16) short Vt[4][64][40];

    int tid = threadIdx.x, w = tid >> 6, lane = tid & 63;
    int raw = (int)blockIdx.x;
    int xcd = raw & 7;
    int kv = xcd & 3, b = xcd >> 2;
    int i5 = raw >> 3;                  // [0,64)
    int x = i5 & 15, hh = i5 >> 4;      // x: pair+e, hh: head-in-group
    int h = kv * G_ + hh;
    int p = x >> 1, e = x & 1;
    int qtA = p, qtB = 15 - p;          // 128-row q-tiles
    int r = lane & 15, kq = lane >> 4;
    bool w4 = (w < 4);
    float lam = lam_p[0];

    floatx4 acc[2][4];
    floatx4 accl[2];
    short8 qa[2][2];

    const short* vbase = vtb + (long)(b * KV_ + kv) * 64 * S_;
    const float c1 = 0.18033688f, nc4 = -3.7570e-7f, zoff = -17.3123405f;
    const short one_bf = (short)0x3F80;
    short8 ones8 = {one_bf, one_bf, one_bf, one_bf, one_bf, one_bf, one_bf, one_bf};

    int krow0 = tid >> 4, kcs0 = ((tid & 15) ^ (krow0 & 7)) * 8;
    const short* kgb = kbuf + ((long)b * S_ * KV_ + kv) * 128;
    int vd = (tid >> 2) & 63, vch = tid & 3;   // V chunk within a 64x64 tile (per wave-half)
    int vsel = w4 ? 0 : 1;                     // which tile of the pair this wave stages

    auto issueK = [&](int buf, int ki) {
        long rb = (long)(ki * 32) * (KV_ * 128);
        gload_lds16(kgb + rb + (long)krow0 * (KV_ * 128) + kcs0, &Ks[buf][0][0] + w * 512);
    };
    auto loadV = [&](int kb) {
        return *(const short8*)(vbase + (long)vd * S_ + kb + vch * 8);
    };

    auto reset_acc = [&]() {
#pragma unroll
        for (int m = 0; m < 2; ++m) {
            accl[m] = {0.f, 0.f, 0.f, 0.f};
#pragma unroll
            for (int dt = 0; dt < 4; ++dt) acc[m][dt] = {0.f, 0.f, 0.f, 0.f};
        }
    };
    auto load_q = [&](int q0) {
        const short* qrow = qb + ((long)(b * S_ + q0 + r) * H_ + h) * 128;
        qa[0][0] = *(const short8*)(qrow + kq * 8);
        qa[0][1] = *(const short8*)(qrow + 32 + kq * 8);
        qa[1][0] = *(const short8*)(qrow + 64 + kq * 8);
        qa[1][1] = *(const short8*)(qrow + 96 + kq * 8);
    };

    auto tile_compute = [&](int bk, int cv, int kb, int q0, bool domask) {
        int rel = q0 + r - kb;
        short8 vb[4];
#pragma unroll
        for (int dt = 0; dt < 4; ++dt) {
            const short* vrow = &Vt[cv][dt * 16 + r][0];
            int2v lo = *(const int2v*)(vrow + 4 * kq);
            int2v hi = *(const int2v*)(vrow + 16 + 4 * kq);
            vb[dt] = __builtin_bit_cast(short8, int4v{lo[0], lo[1], hi[0], hi[1]});
        }
#pragma unroll
        for (int m = 0; m < 2; ++m) {
            floatx4 sacc[2];
            __builtin_amdgcn_s_setprio(1);
#pragma unroll
            for (int nt = 0; nt < 2; ++nt) {
                sacc[nt] = {0.f, 0.f, 0.f, 0.f};
                const short* row = &Ks[bk][nt * 16 + r][0];
                short8 a0 = *(const short8*)(row + (((m * 8) + kq) ^ (r & 7)) * 8);
                short8 a1 = *(const short8*)(row + (((m * 8) + 4 + kq) ^ (r & 7)) * 8);
                sacc[nt] = __builtin_amdgcn_mfma_f32_16x16x32_bf16(a0, qa[m][0], sacc[nt], 0, 0, 0);
                sacc[nt] = __builtin_amdgcn_mfma_f32_16x16x32_bf16(a1, qa[m][1], sacc[nt], 0, 0, 0);
            }
            __builtin_amdgcn_s_setprio(0);
            float pv[2][4];
#pragma unroll
            for (int nt = 0; nt < 2; ++nt)
#pragma unroll
                for (int j = 0; j < 4; ++j) {
                    float rawv = sacc[nt][j];
                    float r2 = rawv * rawv;
                    float z = fmaf(rawv, fmaf(r2, nc4, c1), zoff);
                    pv[nt][j] = __builtin_amdgcn_exp2f(z);
                }
            if (domask) {
#pragma unroll
                for (int nt = 0; nt < 2; ++nt)
#pragma unroll
                    for (int j = 0; j < 4; ++j)
                        if (nt * 16 + kq * 4 + j > rel) pv[nt][j] = 0.f;
            }
            int d0 = cvt_pk_bf16(pv[0][0], pv[0][1]);
            int d1 = cvt_pk_bf16(pv[0][2], pv[0][3]);
            int d2 = cvt_pk_bf16(pv[1][0], pv[1][1]);
            int d3 = cvt_pk_bf16(pv[1][2], pv[1][3]);
            short8 pa8 = __builtin_bit_cast(short8, int4v{d0, d1, d2, d3});
            __builtin_amdgcn_s_setprio(1);
#pragma unroll
            for (int dt = 0; dt < 4; ++dt)
                acc[m][dt] = __builtin_amdgcn_mfma_f32_16x16x32_bf16(
                    pa8, vb[dt], acc[m][dt], 0, 0, 0);
            accl[m] = __builtin_amdgcn_mfma_f32_16x16x32_bf16(pa8, ones8, accl[m], 0, 0, 0);
            __builtin_amdgcn_s_setprio(0);
        }
    };

    // run over 32-k-tiles [ki0, ki1), two tiles per barrier
    auto run = [&](int qt, int ki0, int ki1, bool diag) {
        int q0 = qt * 128 + w * 16;
        load_q(q0);
        reset_acc();
        int nseg = ki1 - ki0;
        issueK(0, ki0);
        if (nseg > 1) issueK(1, ki0 + 1);
        short8 rva = {};
        if (vsel < nseg) rva = loadV((ki0 + vsel) * 32);
        int ii = 0;
        for (; ii + 1 < nseg; ii += 2) {
            int vb0 = 2 * ((ii >> 1) & 1);        // V bufs {0,1} or {2,3}
            *(short8*)&Vt[vb0 + vsel][vd][vch * 8] = rva;
            asm volatile("s_waitcnt vmcnt(0)" ::: "memory");
            asm volatile("s_waitcnt lgkmcnt(0)" ::: "memory");
            __builtin_amdgcn_sched_barrier(0);
            __builtin_amdgcn_s_barrier();
            if (ii + 2 < nseg) {                   // issue pair p+1 (after barrier: race-free)
                issueK((ii + 2) & 3, ki0 + ii + 2);
                if (ii + 3 < nseg) issueK((ii + 3) & 3, ki0 + ii + 3);
                int nxt = ii + 2 + vsel;
                if (nxt < nseg) rva = loadV((ki0 + nxt) * 32);
            }
            int ki = ki0 + ii;
            tile_compute(ii & 3, vb0, ki * 32, q0, diag && (ki >= 4 * qt));
            tile_compute((ii + 1) & 3, vb0 + 1, (ki + 1) * 32, q0,
                         diag && (ki + 1 >= 4 * qt));
        }
        if (ii < nseg) {                           // odd tail (not hit: all nseg even)
            int vb0 = 2 * ((ii >> 1) & 1);
            if (w4) *(short8*)&Vt[vb0][vd][vch * 8] = rva;
            asm volatile("s_waitcnt vmcnt(0)" ::: "memory");
            asm volatile("s_waitcnt lgkmcnt(0)" ::: "memory");
            __builtin_amdgcn_sched_barrier(0);
            __builtin_amdgcn_s_barrier();
            int ki = ki0 + ii;
            tile_compute(ii & 3, vb0, ki * 32, q0, diag && (ki >= 4 * qt));
        }
        __builtin_amdgcn_s_barrier();   // protect LDS reuse across runs
    };

    if (e == 0) {
        run(qtA, 0, 4 * qtA + 4, true);
        {
            int q0 = qtA * 128 + w * 16;
#pragma unroll
            for (int j = 0; j < 4; ++j) {
                float i1 = 1.f / accl[0][j];
                float i2 = lam / accl[1][j];
                int qr = q0 + kq * 4 + j;
                __hip_bfloat16* orow = ob + ((long)(b * S_ + qr) * H_ + h) * 64;
#pragma unroll
                for (int dt = 0; dt < 4; ++dt) {
                    float val = acc[0][dt][j] * i1 - acc[1][dt][j] * i2;
                    orow[dt * 16 + r] = __float2bfloat16(val);
                }
            }
        }
        run(qtB, 0, 30 - 4 * p, false);             // k-prefix of qtB
    } else {
        run(qtB, 30 - 4 * p, 64 - 4 * p, true);     // k-suffix incl diagonal
    }

    // write packed partial: slot = (b*H+h)*8 + (qtB-8), half = e; dword = (m0,m1) bf16x2
    {
        long slot = (long)(b * H_ + h) * 8 + (qtB - 8);
        long base = (slot * 2 + e) * 8192L;
        int qloc = w * 16 + kq * 4;
#pragma unroll
        for (int dt = 0; dt < 4; ++dt)
#pragma unroll
            for (int j = 0; j < 4; ++j)
                part[base + (qloc + j) * 64 + dt * 16 + r] =
                    (unsigned)cvt_pk_bf16(acc[0][dt][j], acc[1][dt][j]);
        if (r == 0) {
#pragma unroll
            for (int m = 0; m < 2; ++m)
#pragma unroll
                for (int j = 0; j < 4; ++j)
                    lpart[((slot * 2 + e) * 2 + m) * 128 + qloc + j] = accl[m][j];
        }
    }
}

// ---------------- merge packed partials for qt128 in [8,16) ----------
__global__ __launch_bounds__(256) void attn_merge_kernel(const unsigned* __restrict__ part,
                                                         const float* __restrict__ lpart,
                                                         __hip_bfloat16* __restrict__ ob,
                                                         const float* __restrict__ lam_p) {
    long sid = blockIdx.x;               // (b*H+h)*8 + (qt-8), 256 slots
    int t8 = sid & 7;
    int h = (sid >> 3) & (H_ - 1);
    int b = (int)(sid >> 7);
    int qt = 8 + t8;
    float lam = lam_p[0];
    const unsigned* p0 = part + sid * 2 * 8192L;
    const unsigned* p1 = p0 + 8192;
    const float* l0 = lpart + sid * 512L;    // e=0: m0 at +0, m1 at +128
    const float* l1 = l0 + 256;              // e=1
    int tid = threadIdx.x;
#pragma unroll
    for (int i = 0; i < 32; ++i) {
        int idx = i * 256 + tid;
        int q = idx >> 6, d = idx & 63;
        unsigned u0 = p0[q * 64 + d], u1 = p1[q * 64 + d];
        float a1 = bf16lo(u0) + bf16lo(u1);
        float a2 = bf16hi(u0) + bf16hi(u1);
        float L1 = l0[q] + l1[q];
        float L2 = l0[128 + q] + l1[128 + q];
        float val = a1 / L1 - lam * (a2 / L2);
        ob[((long)(b * S_ + qt * 128 + q) * H_ + h) * 64 + d] = __float2bfloat16(val);
    }
}

// ---------------- launch ----------------
extern "C" void kernel_launch(void* const* d_in, const int* in_sizes, int n_in,
                              void* d_out, int out_size, void* d_ws, size_t ws_size,
                              hipStream_t stream) {
    const float* x     = (const float*)d_in[0];
    const float* freqs = (const float*)d_in[1];
    const float* wq    = (const float*)d_in[2];
    const float* wk    = (const float*)d_in[3];
    const float* wv    = (const float*)d_in[4];
    const float* wo    = (const float*)d_in[5];
    const float* qnw   = (const float*)d_in[6];
    const float* knw   = (const float*)d_in[7];
    const float* lam   = (const float*)d_in[8];
    float* out = (float*)d_out;

    const int T = B_ * S_;
    char* ws = (char*)d_ws;
    size_t off = 0;
    auto alloc = [&](size_t bytes) {
        void* p = ws + off;
        off += (bytes + 255) & ~(size_t)255;
        return p;
    };
    __hip_bfloat16* xb   = (__hip_bfloat16*)alloc((size_t)T * D_ * 2);
    __hip_bfloat16* wcat = (__hip_bfloat16*)alloc((size_t)NCAT * D_ * 2);
    __hip_bfloat16* wob  = (__hip_bfloat16*)alloc((size_t)D_ * D_ * 2);
    __hip_bfloat16* qb16 = (__hip_bfloat16*)alloc((size_t)T * 2 * H_ * HD_ * 2);
    __hip_bfloat16* kb16 = (__hip_bfloat16*)alloc((size_t)T * 2 * KV_ * HD_ * 2);
    __hip_bfloat16* vT   = (__hip_bfloat16*)alloc((size_t)B_ * KV_ * HD_ * S_ * 2);
    unsigned* part = (unsigned*)alloc((size_t)256 * 2 * 8192 * 4);
    float* lpart   = (float*)alloc((size_t)256 * 2 * 2 * 128 * 4);
    __hip_bfloat16* aob  = xb;   // xb dead after QKV GEMM; same size

    // fused cvt: x, wq, wk, wv, wo (wcat segments are contiguous)
    cvt5_kernel<<<dim3(2048, 5), 256, 0, stream>>>(
        x, wq, wk, wv, wo,
        xb, wcat, wcat + (size_t)2 * H_ * HD_ * D_,
        wcat + (size_t)(2 * H_ * HD_ + 2 * KV_ * HD_) * D_, wob,
        T * D_, 2 * H_ * HD_ * D_, 2 * KV_ * HD_ * D_, KV_ * HD_ * D_, D_ * D_);

    // fused QKV projection + RMSNorm + RoPE + V-transpose
    gemm_qkv_fused<<<dim3(NCAT / 128, T / 128), 256, 0, stream>>>(
        (const short*)xb, (const short*)wcat, qb16, kb16, vT,
        freqs, qnw, knw, T, NCAT, D_);

    // differential causal attention + merge
    attn_kernel<<<512, 512, 0, stream>>>(
        (const short*)qb16, (const short*)kb16, (const short*)vT, aob, part, lpart, lam);
    attn_merge_kernel<<<256, 256, 0, stream>>>(part, lpart, aob, lam);

    // output projection -> f32
    gemm_bt_lds<float><<<dim3(D_ / 128, T / 128), 256, 0, stream>>>(
        (const short*)aob, (const short*)wob, out, T, D_, D_);
}

// Round 18
// 154.156 us; speedup vs baseline: 1.3743x; 1.0156x over previous
//
#include <hip/hip_runtime.h>
#include <hip/hip_bf16.h>

#define B_ 2
#define S_ 2048
#define D_ 1024
#define H_ 16
#define KV_ 4
#define HD_ 64
#define G_ (H_ / KV_)
#define NCAT 2816          // 2*H*HD + 2*KV*HD + KV*HD
#define VOFF 2560          // col offset of V block in fused QKV output

typedef __attribute__((ext_vector_type(8))) short short8;
typedef __attribute__((ext_vector_type(4))) short short4v;
typedef __attribute__((ext_vector_type(2))) int int2v;
typedef __attribute__((ext_vector_type(4))) int int4v;
typedef __attribute__((ext_vector_type(4))) float floatx4;

using gvoid_p = const __attribute__((address_space(1))) void*;
using lvoid_p = __attribute__((address_space(3))) void*;

__device__ inline void gload_lds16(const short* g, short* l) {
    __builtin_amdgcn_global_load_lds((gvoid_p)(const void*)g, (lvoid_p)(void*)l, 16, 0, 0);
}

__device__ inline int cvt_pk_bf16(float lo, float hi) {
    int r;
    asm volatile("v_cvt_pk_bf16_f32 %0, %1, %2" : "=v"(r) : "v"(lo), "v"(hi));
    return r;
}

__device__ inline float bf16lo(unsigned u) {
    return __builtin_bit_cast(float, u << 16);
}
__device__ inline float bf16hi(unsigned u) {
    return __builtin_bit_cast(float, u & 0xffff0000u);
}

// ---------------- fused fp32 -> bf16 convert (5 segments, float4 vectorized) -------------
__global__ void cvt5_kernel(const float* s0, const float* s1, const float* s2,
                            const float* s3, const float* s4,
                            __hip_bfloat16* d0, __hip_bfloat16* d1, __hip_bfloat16* d2,
                            __hip_bfloat16* d3, __hip_bfloat16* d4,
                            int n0, int n1, int n2, int n3, int n4) {
    const float* s; __hip_bfloat16* d; int n;
    switch (blockIdx.y) {
        case 0: s = s0; d = d0; n = n0; break;
        case 1: s = s1; d = d1; n = n1; break;
        case 2: s = s2; d = d2; n = n2; break;
        case 3: s = s3; d = d3; n = n3; break;
        default: s = s4; d = d4; n = n4; break;
    }
    int nv = n >> 2;
    for (int i = blockIdx.x * blockDim.x + threadIdx.x; i < nv;
         i += gridDim.x * blockDim.x) {
        floatx4 v = ((const floatx4*)s)[i];
        short4v o;
#pragma unroll
        for (int e = 0; e < 4; ++e) {
            __hip_bfloat16 hh = __float2bfloat16(v[e]);
            o[e] = __builtin_bit_cast(short, hh);
        }
        ((short4v*)d)[i] = o;
    }
}

// ---------------- QKV GEMM with FUSED RMSNorm+RoPE epilogue ----------------
__global__ __launch_bounds__(256) void gemm_qkv_fused(const short* __restrict__ A,
                                                      const short* __restrict__ Bm,
                                                      __hip_bfloat16* __restrict__ qout,
                                                      __hip_bfloat16* __restrict__ kout,
                                                      __hip_bfloat16* __restrict__ vout,
                                                      const float* __restrict__ freqs,
                                                      const float* __restrict__ qnw,
                                                      const float* __restrict__ knw,
                                                      int M, int N, int K) {
    __shared__ __align__(16) short As[2][128 * 32];
    __shared__ __align__(16) short Bs[2][128 * 32];
    int tid = threadIdx.x;
    int wid = tid >> 6, lane = tid & 63;
    int wr = wid >> 1, wc = wid & 1;
    int r = lane & 15, kq = lane >> 4;

    int nwg = gridDim.x * gridDim.y;
    int orig = blockIdx.y * gridDim.x + blockIdx.x;
    int wg = (orig & 7) * (nwg >> 3) + (orig >> 3);
    int bx = wg % gridDim.x, by = wg / gridDim.x;

    long m0 = (long)by * 128;
    long n0 = (long)bx * 128;

    const short* gA0 = A + (m0 + (tid >> 2)) * (long)K + (tid & 3) * 8;
    const short* gA1 = A + (m0 + 64 + (tid >> 2)) * (long)K + (tid & 3) * 8;
    const short* gB0 = Bm + (n0 + (tid >> 2)) * (long)K + (tid & 3) * 8;
    const short* gB1 = Bm + (n0 + 64 + (tid >> 2)) * (long)K + (tid & 3) * 8;

    auto stage = [&](int buf, int k0) {
        gload_lds16(gA0 + k0, &As[buf][wid * 512]);
        gload_lds16(gA1 + k0, &As[buf][2048 + wid * 512]);
        gload_lds16(gB0 + k0, &Bs[buf][wid * 512]);
        gload_lds16(gB1 + k0, &Bs[buf][2048 + wid * 512]);
    };

    floatx4 acc[4][4];
#pragma unroll
    for (int i = 0; i < 4; ++i)
#pragma unroll
        for (int j = 0; j < 4; ++j) acc[i][j] = {0.f, 0.f, 0.f, 0.f};

    int nt = K >> 5;
    stage(0, 0);
    for (int t = 0; t < nt; ++t) {
        int cur = t & 1;
        __builtin_amdgcn_s_barrier();
        if (t + 1 < nt) {
            stage(cur ^ 1, (t + 1) << 5);
            asm volatile("s_waitcnt vmcnt(4)" ::: "memory");
        } else {
            asm volatile("s_waitcnt vmcnt(0)" ::: "memory");
        }
        __builtin_amdgcn_sched_barrier(0);
        __builtin_amdgcn_s_barrier();
        short8 a[4], b[4];
#pragma unroll
        for (int mi = 0; mi < 4; ++mi)
            a[mi] = *(const short8*)&As[cur][(wr * 64 + mi * 16 + r) * 32 + kq * 8];
#pragma unroll
        for (int ni = 0; ni < 4; ++ni)
            b[ni] = *(const short8*)&Bs[cur][(wc * 64 + ni * 16 + r) * 32 + kq * 8];
#pragma unroll
        for (int mi = 0; mi < 4; ++mi)
#pragma unroll
            for (int ni = 0; ni < 4; ++ni)
                acc[mi][ni] = __builtin_amdgcn_mfma_f32_16x16x32_bf16(
                    a[mi], b[ni], acc[mi][ni], 0, 0, 0);
    }

    // ---------- fused epilogue ----------
    int col_l = lane & 15;
    int gbase = (int)n0 + wc * 64;
    int par = col_l & 1;
    if (gbase < VOFF) {
        const float* wnorm = (gbase < 2048) ? qnw : knw;
        float wv4[4];
        int fo[4];
#pragma unroll
        for (int ni = 0; ni < 4; ++ni) {
            wv4[ni] = wnorm[ni * 16 + col_l];
            fo[ni] = ni * 16 + (col_l >> 1) * 2;
        }
        __hip_bfloat16* outp;
        long tstride;
        int cbase;
        if (gbase < 2048) { outp = qout; tstride = 2048; cbase = gbase; }
        else              { outp = kout; tstride = 512;  cbase = gbase - 2048; }
#pragma unroll
        for (int mi = 0; mi < 4; ++mi) {
#pragma unroll
            for (int j = 0; j < 4; ++j) {
                int t = (int)m0 + wr * 64 + mi * 16 + kq * 4 + j;
                float ss = 0.f;
#pragma unroll
                for (int ni = 0; ni < 4; ++ni)
                    ss = fmaf(acc[mi][ni][j], acc[mi][ni][j], ss);
                ss += __shfl_xor(ss, 1); ss += __shfl_xor(ss, 2);
                ss += __shfl_xor(ss, 4); ss += __shfl_xor(ss, 8);
                float rr = rsqrtf(ss * (1.f / 64.f) + 1e-6f);
                const float* fb = freqs + (long)(t & (S_ - 1)) * 64;
                __hip_bfloat16* orow = outp + (long)t * tstride + cbase;
#pragma unroll
                for (int ni = 0; ni < 4; ++ni) {
                    float xv = acc[mi][ni][j] * rr * wv4[ni];
                    float pp = __shfl_xor(xv, 1);
                    float cc = fb[fo[ni]], sn = fb[fo[ni] + 1];
                    float y = par ? fmaf(pp, sn, xv * cc) : fmaf(xv, cc, -(pp * sn));
                    orow[ni * 16 + col_l] = __float2bfloat16(y);
                }
            }
        }
    } else {
        int kvv = (gbase - VOFF) >> 6;
#pragma unroll
        for (int mi = 0; mi < 4; ++mi) {
#pragma unroll
            for (int j = 0; j < 4; ++j) {
                int t = (int)m0 + wr * 64 + mi * 16 + kq * 4 + j;
                int bb = t >> 11, st = t & (S_ - 1);
                __hip_bfloat16* vcol = vout + ((long)(bb * KV_ + kvv) * 64) * S_ + st;
#pragma unroll
                for (int ni = 0; ni < 4; ++ni)
                    vcol[(long)(ni * 16 + col_l) * S_] = __float2bfloat16(acc[mi][ni][j]);
            }
        }
    }
}

// ---------------- NT GEMM, 128x64 tile (out-projection): 512 blocks = 2/CU ----------
// Waves 2x2, wave tile 64x32 (acc[4][2]). A: 2 chunks/thread; B: 64x32 tile = 256
// chunks = 1/thread. 3 gloads/thread/tile -> steady vmcnt(3). Same 2-phase pipeline
// and XCD swizzle (nwg=512 %8==0).
__global__ __launch_bounds__(256) void gemm_bt_n64(const short* __restrict__ A,
                                                   const short* __restrict__ Bm,
                                                   float* __restrict__ C,
                                                   int M, int N, int K) {
    __shared__ __align__(16) short As[2][128 * 32];
    __shared__ __align__(16) short Bs[2][64 * 32];
    int tid = threadIdx.x;
    int wid = tid >> 6, lane = tid & 63;
    int wr = wid >> 1, wc = wid & 1;
    int r = lane & 15, kq = lane >> 4;

    int nwg = gridDim.x * gridDim.y;
    int orig = blockIdx.y * gridDim.x + blockIdx.x;
    int wg = (orig & 7) * (nwg >> 3) + (orig >> 3);
    int bx = wg % gridDim.x, by = wg / gridDim.x;

    long m0 = (long)by * 128;
    long n0 = (long)bx * 64;

    const short* gA0 = A + (m0 + (tid >> 2)) * (long)K + (tid & 3) * 8;
    const short* gA1 = A + (m0 + 64 + (tid >> 2)) * (long)K + (tid & 3) * 8;
    const short* gB0 = Bm + (n0 + (tid >> 2)) * (long)K + (tid & 3) * 8;

    auto stage = [&](int buf, int k0) {
        gload_lds16(gA0 + k0, &As[buf][wid * 512]);
        gload_lds16(gA1 + k0, &As[buf][2048 + wid * 512]);
        gload_lds16(gB0 + k0, &Bs[buf][wid * 512]);
    };

    floatx4 acc[4][2];
#pragma unroll
    for (int i = 0; i < 4; ++i)
#pragma unroll
        for (int j = 0; j < 2; ++j) acc[i][j] = {0.f, 0.f, 0.f, 0.f};

    int nt = K >> 5;
    stage(0, 0);
    for (int t = 0; t < nt; ++t) {
        int cur = t & 1;
        __builtin_amdgcn_s_barrier();
        if (t + 1 < nt) {
            stage(cur ^ 1, (t + 1) << 5);
            asm volatile("s_waitcnt vmcnt(3)" ::: "memory");
        } else {
            asm volatile("s_waitcnt vmcnt(0)" ::: "memory");
        }
        __builtin_amdgcn_sched_barrier(0);
        __builtin_amdgcn_s_barrier();
        short8 a[4], b[2];
#pragma unroll
        for (int mi = 0; mi < 4; ++mi)
            a[mi] = *(const short8*)&As[cur][(wr * 64 + mi * 16 + r) * 32 + kq * 8];
#pragma unroll
        for (int ni = 0; ni < 2; ++ni)
            b[ni] = *(const short8*)&Bs[cur][(wc * 32 + ni * 16 + r) * 32 + kq * 8];
#pragma unroll
        for (int mi = 0; mi < 4; ++mi)
#pragma unroll
            for (int ni = 0; ni < 2; ++ni)
                acc[mi][ni] = __builtin_amdgcn_mfma_f32_16x16x32_bf16(
                    a[mi], b[ni], acc[mi][ni], 0, 0, 0);
    }
    int col_l = lane & 15, row_l = (lane >> 4) * 4;
#pragma unroll
    for (int mi = 0; mi < 4; ++mi)
#pragma unroll
        for (int ni = 0; ni < 2; ++ni) {
            long col = n0 + wc * 32 + ni * 16 + col_l;
            long row0 = m0 + wr * 64 + mi * 16 + row_l;
#pragma unroll
            for (int j = 0; j < 4; ++j)
                C[(row0 + j) * N + col] = acc[mi][ni][j];
        }
}

// ---------------- differential causal attention: paired-tile loop (r17, passed) ----------
__global__ __launch_bounds__(512, 4) void attn_kernel(const short* __restrict__ qb,
                                                      const short* __restrict__ kbuf,
                                                      const short* __restrict__ vtb,
                                                      __hip_bfloat16* __restrict__ ob,
                                                      unsigned* __restrict__ part,
                                                      float* __restrict__ lpart,
                                                      const float* __restrict__ lam_p) {
    __shared__ __align__(16) short Ks[4][32][128];
    __shared__ __align__(16) short Vt[4][64][40];

    int tid = threadIdx.x, w = tid >> 6, lane = tid & 63;
    int raw = (int)blockIdx.x;
    int xcd = raw & 7;
    int kv = xcd & 3, b = xcd >> 2;
    int i5 = raw >> 3;                  // [0,64)
    int x = i5 & 15, hh = i5 >> 4;      // x: pair+e, hh: head-in-group
    int h = kv * G_ + hh;
    int p = x >> 1, e = x & 1;
    int qtA = p, qtB = 15 - p;          // 128-row q-tiles
    int r = lane & 15, kq = lane >> 4;
    bool w4 = (w < 4);
    float lam = lam_p[0];

    floatx4 acc[2][4];
    floatx4 accl[2];
    short8 qa[2][2];

    const short* vbase = vtb + (long)(b * KV_ + kv) * 64 * S_;
    const float c1 = 0.18033688f, nc4 = -3.7570e-7f, zoff = -17.3123405f;
    const short one_bf = (short)0x3F80;
    short8 ones8 = {one_bf, one_bf, one_bf, one_bf, one_bf, one_bf, one_bf, one_bf};

    int krow0 = tid >> 4, kcs0 = ((tid & 15) ^ (krow0 & 7)) * 8;
    const short* kgb = kbuf + ((long)b * S_ * KV_ + kv) * 128;
    int vd = (tid >> 2) & 63, vch = tid & 3;   // V chunk within a 64x64 tile (per wave-half)
    int vsel = w4 ? 0 : 1;                     // which tile of the pair this wave stages

    auto issueK = [&](int buf, int ki) {
        long rb = (long)(ki * 32) * (KV_ * 128);
        gload_lds16(kgb + rb + (long)krow0 * (KV_ * 128) + kcs0, &Ks[buf][0][0] + w * 512);
    };
    auto loadV = [&](int kb) {
        return *(const short8*)(vbase + (long)vd * S_ + kb + vch * 8);
    };

    auto reset_acc = [&]() {
#pragma unroll
        for (int m = 0; m < 2; ++m) {
            accl[m] = {0.f, 0.f, 0.f, 0.f};
#pragma unroll
            for (int dt = 0; dt < 4; ++dt) acc[m][dt] = {0.f, 0.f, 0.f, 0.f};
        }
    };
    auto load_q = [&](int q0) {
        const short* qrow = qb + ((long)(b * S_ + q0 + r) * H_ + h) * 128;
        qa[0][0] = *(const short8*)(qrow + kq * 8);
        qa[0][1] = *(const short8*)(qrow + 32 + kq * 8);
        qa[1][0] = *(const short8*)(qrow + 64 + kq * 8);
        qa[1][1] = *(const short8*)(qrow + 96 + kq * 8);
    };

    auto tile_compute = [&](int bk, int cv, int kb, int q0, bool domask) {
        int rel = q0 + r - kb;
        short8 vb[4];
#pragma unroll
        for (int dt = 0; dt < 4; ++dt) {
            const short* vrow = &Vt[cv][dt * 16 + r][0];
            int2v lo = *(const int2v*)(vrow + 4 * kq);
            int2v hi = *(const int2v*)(vrow + 16 + 4 * kq);
            vb[dt] = __builtin_bit_cast(short8, int4v{lo[0], lo[1], hi[0], hi[1]});
        }
#pragma unroll
        for (int m = 0; m < 2; ++m) {
            floatx4 sacc[2];
            __builtin_amdgcn_s_setprio(1);
#pragma unroll
            for (int nt = 0; nt < 2; ++nt) {
                sacc[nt] = {0.f, 0.f, 0.f, 0.f};
                const short* row = &Ks[bk][nt * 16 + r][0];
                short8 a0 = *(const short8*)(row + (((m * 8) + kq) ^ (r & 7)) * 8);
                short8 a1 = *(const short8*)(row + (((m * 8) + 4 + kq) ^ (r & 7)) * 8);
                sacc[nt] = __builtin_amdgcn_mfma_f32_16x16x32_bf16(a0, qa[m][0], sacc[nt], 0, 0, 0);
                sacc[nt] = __builtin_amdgcn_mfma_f32_16x16x32_bf16(a1, qa[m][1], sacc[nt], 0, 0, 0);
            }
            __builtin_amdgcn_s_setprio(0);
            float pv[2][4];
#pragma unroll
            for (int nt = 0; nt < 2; ++nt)
#pragma unroll
                for (int j = 0; j < 4; ++j) {
                    float rawv = sacc[nt][j];
                    float r2 = rawv * rawv;
                    float z = fmaf(rawv, fmaf(r2, nc4, c1), zoff);
                    pv[nt][j] = __builtin_amdgcn_exp2f(z);
                }
            if (domask) {
#pragma unroll
                for (int nt = 0; nt < 2; ++nt)
#pragma unroll
                    for (int j = 0; j < 4; ++j)
                        if (nt * 16 + kq * 4 + j > rel) pv[nt][j] = 0.f;
            }
            int d0 = cvt_pk_bf16(pv[0][0], pv[0][1]);
            int d1 = cvt_pk_bf16(pv[0][2], pv[0][3]);
            int d2 = cvt_pk_bf16(pv[1][0], pv[1][1]);
            int d3 = cvt_pk_bf16(pv[1][2], pv[1][3]);
            short8 pa8 = __builtin_bit_cast(short8, int4v{d0, d1, d2, d3});
            __builtin_amdgcn_s_setprio(1);
#pragma unroll
            for (int dt = 0; dt < 4; ++dt)
                acc[m][dt] = __builtin_amdgcn_mfma_f32_16x16x32_bf16(
                    pa8, vb[dt], acc[m][dt], 0, 0, 0);
            accl[m] = __builtin_amdgcn_mfma_f32_16x16x32_bf16(pa8, ones8, accl[m], 0, 0, 0);
            __builtin_amdgcn_s_setprio(0);
        }
    };

    // run over 32-k-tiles [ki0, ki1), two tiles per barrier
    auto run = [&](int qt, int ki0, int ki1, bool diag) {
        int q0 = qt * 128 + w * 16;
        load_q(q0);
        reset_acc();
        int nseg = ki1 - ki0;
        issueK(0, ki0);
        if (nseg > 1) issueK(1, ki0 + 1);
        short8 rva = {};
        if (vsel < nseg) rva = loadV((ki0 + vsel) * 32);
        int ii = 0;
        for (; ii + 1 < nseg; ii += 2) {
            int vb0 = 2 * ((ii >> 1) & 1);        // V bufs {0,1} or {2,3}
            *(short8*)&Vt[vb0 + vsel][vd][vch * 8] = rva;
            asm volatile("s_waitcnt vmcnt(0)" ::: "memory");
            asm volatile("s_waitcnt lgkmcnt(0)" ::: "memory");
            __builtin_amdgcn_sched_barrier(0);
            __builtin_amdgcn_s_barrier();
            if (ii + 2 < nseg) {                   // issue pair p+1 (after barrier: race-free)
                issueK((ii + 2) & 3, ki0 + ii + 2);
                if (ii + 3 < nseg) issueK((ii + 3) & 3, ki0 + ii + 3);
                int nxt = ii + 2 + vsel;
                if (nxt < nseg) rva = loadV((ki0 + nxt) * 32);
            }
            int ki = ki0 + ii;
            tile_compute(ii & 3, vb0, ki * 32, q0, diag && (ki >= 4 * qt));
            tile_compute((ii + 1) & 3, vb0 + 1, (ki + 1) * 32, q0,
                         diag && (ki + 1 >= 4 * qt));
        }
        if (ii < nseg) {                           // odd tail (not hit: all nseg even)
            int vb0 = 2 * ((ii >> 1) & 1);
            if (w4) *(short8*)&Vt[vb0][vd][vch * 8] = rva;
            asm volatile("s_waitcnt vmcnt(0)" ::: "memory");
            asm volatile("s_waitcnt lgkmcnt(0)" ::: "memory");
            __builtin_amdgcn_sched_barrier(0);
            __builtin_amdgcn_s_barrier();
            int ki = ki0 + ii;
            tile_compute(ii & 3, vb0, ki * 32, q0, diag && (ki >= 4 * qt));
        }
        __builtin_amdgcn_s_barrier();   // protect LDS reuse across runs
    };

    if (e == 0) {
        run(qtA, 0, 4 * qtA + 4, true);
        {
            int q0 = qtA * 128 + w * 16;
#pragma unroll
            for (int j = 0; j < 4; ++j) {
                float i1 = 1.f / accl[0][j];
                float i2 = lam / accl[1][j];
                int qr = q0 + kq * 4 + j;
                __hip_bfloat16* orow = ob + ((long)(b * S_ + qr) * H_ + h) * 64;
#pragma unroll
                for (int dt = 0; dt < 4; ++dt) {
                    float val = acc[0][dt][j] * i1 - acc[1][dt][j] * i2;
                    orow[dt * 16 + r] = __float2bfloat16(val);
                }
            }
        }
        run(qtB, 0, 30 - 4 * p, false);             // k-prefix of qtB
    } else {
        run(qtB, 30 - 4 * p, 64 - 4 * p, true);     // k-suffix incl diagonal
    }

    // write packed partial: slot = (b*H+h)*8 + (qtB-8), half = e; dword = (m0,m1) bf16x2
    {
        long slot = (long)(b * H_ + h) * 8 + (qtB - 8);
        long base = (slot * 2 + e) * 8192L;
        int qloc = w * 16 + kq * 4;
#pragma unroll
        for (int dt = 0; dt < 4; ++dt)
#pragma unroll
            for (int j = 0; j < 4; ++j)
                part[base + (qloc + j) * 64 + dt * 16 + r] =
                    (unsigned)cvt_pk_bf16(acc[0][dt][j], acc[1][dt][j]);
        if (r == 0) {
#pragma unroll
            for (int m = 0; m < 2; ++m)
#pragma unroll
                for (int j = 0; j < 4; ++j)
                    lpart[((slot * 2 + e) * 2 + m) * 128 + qloc + j] = accl[m][j];
        }
    }
}

// ---------------- merge packed partials for qt128 in [8,16) ----------
__global__ __launch_bounds__(256) void attn_merge_kernel(const unsigned* __restrict__ part,
                                                         const float* __restrict__ lpart,
                                                         __hip_bfloat16* __restrict__ ob,
                                                         const float* __restrict__ lam_p) {
    long sid = blockIdx.x;               // (b*H+h)*8 + (qt-8), 256 slots
    int t8 = sid & 7;
    int h = (sid >> 3) & (H_ - 1);
    int b = (int)(sid >> 7);
    int qt = 8 + t8;
    float lam = lam_p[0];
    const unsigned* p0 = part + sid * 2 * 8192L;
    const unsigned* p1 = p0 + 8192;
    const float* l0 = lpart + sid * 512L;    // e=0: m0 at +0, m1 at +128
    const float* l1 = l0 + 256;              // e=1
    int tid = threadIdx.x;
#pragma unroll
    for (int i = 0; i < 32; ++i) {
        int idx = i * 256 + tid;
        int q = idx >> 6, d = idx & 63;
        unsigned u0 = p0[q * 64 + d], u1 = p1[q * 64 + d];
        float a1 = bf16lo(u0) + bf16lo(u1);
        float a2 = bf16hi(u0) + bf16hi(u1);
        float L1 = l0[q] + l1[q];
        float L2 = l0[128 + q] + l1[128 + q];
        float val = a1 / L1 - lam * (a2 / L2);
        ob[((long)(b * S_ + qt * 128 + q) * H_ + h) * 64 + d] = __float2bfloat16(val);
    }
}

// ---------------- launch ----------------
extern "C" void kernel_launch(void* const* d_in, const int* in_sizes, int n_in,
                              void* d_out, int out_size, void* d_ws, size_t ws_size,
                              hipStream_t stream) {
    const float* x     = (const float*)d_in[0];
    const float* freqs = (const float*)d_in[1];
    const float* wq    = (const float*)d_in[2];
    const float* wk    = (const float*)d_in[3];
    const float* wv    = (const float*)d_in[4];
    const float* wo    = (const float*)d_in[5];
    const float* qnw   = (const float*)d_in[6];
    const float* knw   = (const float*)d_in[7];
    const float* lam   = (const float*)d_in[8];
    float* out = (float*)d_out;

    const int T = B_ * S_;
    char* ws = (char*)d_ws;
    size_t off = 0;
    auto alloc = [&](size_t bytes) {
        void* p = ws + off;
        off += (bytes + 255) & ~(size_t)255;
        return p;
    };
    __hip_bfloat16* xb   = (__hip_bfloat16*)alloc((size_t)T * D_ * 2);
    __hip_bfloat16* wcat = (__hip_bfloat16*)alloc((size_t)NCAT * D_ * 2);
    __hip_bfloat16* wob  = (__hip_bfloat16*)alloc((size_t)D_ * D_ * 2);
    __hip_bfloat16* qb16 = (__hip_bfloat16*)alloc((size_t)T * 2 * H_ * HD_ * 2);
    __hip_bfloat16* kb16 = (__hip_bfloat16*)alloc((size_t)T * 2 * KV_ * HD_ * 2);
    __hip_bfloat16* vT   = (__hip_bfloat16*)alloc((size_t)B_ * KV_ * HD_ * S_ * 2);
    unsigned* part = (unsigned*)alloc((size_t)256 * 2 * 8192 * 4);
    float* lpart   = (float*)alloc((size_t)256 * 2 * 2 * 128 * 4);
    __hip_bfloat16* aob  = xb;   // xb dead after QKV GEMM; same size

    // fused cvt: x, wq, wk, wv, wo (wcat segments are contiguous)
    cvt5_kernel<<<dim3(2048, 5), 256, 0, stream>>>(
        x, wq, wk, wv, wo,
        xb, wcat, wcat + (size_t)2 * H_ * HD_ * D_,
        wcat + (size_t)(2 * H_ * HD_ + 2 * KV_ * HD_) * D_, wob,
        T * D_, 2 * H_ * HD_ * D_, 2 * KV_ * HD_ * D_, KV_ * HD_ * D_, D_ * D_);

    // fused QKV projection + RMSNorm + RoPE + V-transpose
    gemm_qkv_fused<<<dim3(NCAT / 128, T / 128), 256, 0, stream>>>(
        (const short*)xb, (const short*)wcat, qb16, kb16, vT,
        freqs, qnw, knw, T, NCAT, D_);

    // differential causal attention + merge
    attn_kernel<<<512, 512, 0, stream>>>(
        (const short*)qb16, (const short*)kb16, (const short*)vT, aob, part, lpart, lam);
    attn_merge_kernel<<<256, 256, 0, stream>>>(part, lpart, aob, lam);

    // output projection -> f32 (128x64 tiles, 512 blocks = 2/CU)
    gemm_bt_n64<<<dim3(D_ / 64, T / 128), 256, 0, stream>>>(
        (const short*)aob, (const short*)wob, out, T, D_, D_);
}

// Round 19
// 153.496 us; speedup vs baseline: 1.3802x; 1.0043x over previous
//
#include <hip/hip_runtime.h>
#include <hip/hip_bf16.h>

#define B_ 2
#define S_ 2048
#define D_ 1024
#define H_ 16
#define KV_ 4
#define HD_ 64
#define G_ (H_ / KV_)
#define NCAT 2816          // 2*H*HD + 2*KV*HD + KV*HD
#define VOFF 2560          // col offset of V block in fused QKV output

typedef __attribute__((ext_vector_type(8))) short short8;
typedef __attribute__((ext_vector_type(4))) short short4v;
typedef __attribute__((ext_vector_type(2))) int int2v;
typedef __attribute__((ext_vector_type(4))) int int4v;
typedef __attribute__((ext_vector_type(4))) float floatx4;

using gvoid_p = const __attribute__((address_space(1))) void*;
using lvoid_p = __attribute__((address_space(3))) void*;

__device__ inline void gload_lds16(const short* g, short* l) {
    __builtin_amdgcn_global_load_lds((gvoid_p)(const void*)g, (lvoid_p)(void*)l, 16, 0, 0);
}

__device__ inline int cvt_pk_bf16(float lo, float hi) {
    int r;
    asm volatile("v_cvt_pk_bf16_f32 %0, %1, %2" : "=v"(r) : "v"(lo), "v"(hi));
    return r;
}

__device__ inline float bf16lo(unsigned u) {
    return __builtin_bit_cast(float, u << 16);
}
__device__ inline float bf16hi(unsigned u) {
    return __builtin_bit_cast(float, u & 0xffff0000u);
}

// ---------------- fused fp32 -> bf16 convert (5 segments, float4 vectorized) -------------
__global__ void cvt5_kernel(const float* s0, const float* s1, const float* s2,
                            const float* s3, const float* s4,
                            __hip_bfloat16* d0, __hip_bfloat16* d1, __hip_bfloat16* d2,
                            __hip_bfloat16* d3, __hip_bfloat16* d4,
                            int n0, int n1, int n2, int n3, int n4) {
    const float* s; __hip_bfloat16* d; int n;
    switch (blockIdx.y) {
        case 0: s = s0; d = d0; n = n0; break;
        case 1: s = s1; d = d1; n = n1; break;
        case 2: s = s2; d = d2; n = n2; break;
        case 3: s = s3; d = d3; n = n3; break;
        default: s = s4; d = d4; n = n4; break;
    }
    int nv = n >> 2;
    for (int i = blockIdx.x * blockDim.x + threadIdx.x; i < nv;
         i += gridDim.x * blockDim.x) {
        floatx4 v = ((const floatx4*)s)[i];
        short4v o;
#pragma unroll
        for (int e = 0; e < 4; ++e) {
            __hip_bfloat16 hh = __float2bfloat16(v[e]);
            o[e] = __builtin_bit_cast(short, hh);
        }
        ((short4v*)d)[i] = o;
    }
}

// ---------------- QKV GEMM with FUSED RMSNorm+RoPE epilogue ----------------
// Triple-buffer LDS, ONE barrier per k-step, depth-2 prefetch: per iter t:
// vmcnt(4) [own t-DMAs drained] -> barrier [all waves' t-DMAs published] ->
// issue stage(t+2)->buf (t+2)%3 [last read by compute(t-1), pre-barrier: race-free]
// -> compute buf t%3.
__global__ __launch_bounds__(256) void gemm_qkv_fused(const short* __restrict__ A,
                                                      const short* __restrict__ Bm,
                                                      __hip_bfloat16* __restrict__ qout,
                                                      __hip_bfloat16* __restrict__ kout,
                                                      __hip_bfloat16* __restrict__ vout,
                                                      const float* __restrict__ freqs,
                                                      const float* __restrict__ qnw,
                                                      const float* __restrict__ knw,
                                                      int M, int N, int K) {
    __shared__ __align__(16) short As[3][128 * 32];
    __shared__ __align__(16) short Bs[3][128 * 32];
    int tid = threadIdx.x;
    int wid = tid >> 6, lane = tid & 63;
    int wr = wid >> 1, wc = wid & 1;
    int r = lane & 15, kq = lane >> 4;

    int nwg = gridDim.x * gridDim.y;
    int orig = blockIdx.y * gridDim.x + blockIdx.x;
    int wg = (orig & 7) * (nwg >> 3) + (orig >> 3);
    int bx = wg % gridDim.x, by = wg / gridDim.x;

    long m0 = (long)by * 128;
    long n0 = (long)bx * 128;

    const short* gA0 = A + (m0 + (tid >> 2)) * (long)K + (tid & 3) * 8;
    const short* gA1 = A + (m0 + 64 + (tid >> 2)) * (long)K + (tid & 3) * 8;
    const short* gB0 = Bm + (n0 + (tid >> 2)) * (long)K + (tid & 3) * 8;
    const short* gB1 = Bm + (n0 + 64 + (tid >> 2)) * (long)K + (tid & 3) * 8;

    auto stage = [&](int buf, int k0) {
        gload_lds16(gA0 + k0, &As[buf][wid * 512]);
        gload_lds16(gA1 + k0, &As[buf][2048 + wid * 512]);
        gload_lds16(gB0 + k0, &Bs[buf][wid * 512]);
        gload_lds16(gB1 + k0, &Bs[buf][2048 + wid * 512]);
    };

    floatx4 acc[4][4];
#pragma unroll
    for (int i = 0; i < 4; ++i)
#pragma unroll
        for (int j = 0; j < 4; ++j) acc[i][j] = {0.f, 0.f, 0.f, 0.f};

    int nt = K >> 5;
    stage(0, 0);
    if (nt > 1) stage(1, 32);
    int bk = 0;
    for (int t = 0; t < nt; ++t) {
        if (t + 1 < nt) asm volatile("s_waitcnt vmcnt(4)" ::: "memory");
        else            asm volatile("s_waitcnt vmcnt(0)" ::: "memory");
        __builtin_amdgcn_sched_barrier(0);
        __builtin_amdgcn_s_barrier();
        if (t + 2 < nt) {
            int bk2 = bk + 2; if (bk2 >= 3) bk2 -= 3;
            stage(bk2, (t + 2) << 5);
        }
        short8 a[4], b[4];
#pragma unroll
        for (int mi = 0; mi < 4; ++mi)
            a[mi] = *(const short8*)&As[bk][(wr * 64 + mi * 16 + r) * 32 + kq * 8];
#pragma unroll
        for (int ni = 0; ni < 4; ++ni)
            b[ni] = *(const short8*)&Bs[bk][(wc * 64 + ni * 16 + r) * 32 + kq * 8];
#pragma unroll
        for (int mi = 0; mi < 4; ++mi)
#pragma unroll
            for (int ni = 0; ni < 4; ++ni)
                acc[mi][ni] = __builtin_amdgcn_mfma_f32_16x16x32_bf16(
                    a[mi], b[ni], acc[mi][ni], 0, 0, 0);
        bk = (bk == 2) ? 0 : bk + 1;
    }

    // ---------- fused epilogue ----------
    int col_l = lane & 15;
    int gbase = (int)n0 + wc * 64;
    int par = col_l & 1;
    if (gbase < VOFF) {
        const float* wnorm = (gbase < 2048) ? qnw : knw;
        float wv4[4];
        int fo[4];
#pragma unroll
        for (int ni = 0; ni < 4; ++ni) {
            wv4[ni] = wnorm[ni * 16 + col_l];
            fo[ni] = ni * 16 + (col_l >> 1) * 2;
        }
        __hip_bfloat16* outp;
        long tstride;
        int cbase;
        if (gbase < 2048) { outp = qout; tstride = 2048; cbase = gbase; }
        else              { outp = kout; tstride = 512;  cbase = gbase - 2048; }
#pragma unroll
        for (int mi = 0; mi < 4; ++mi) {
#pragma unroll
            for (int j = 0; j < 4; ++j) {
                int t = (int)m0 + wr * 64 + mi * 16 + kq * 4 + j;
                float ss = 0.f;
#pragma unroll
                for (int ni = 0; ni < 4; ++ni)
                    ss = fmaf(acc[mi][ni][j], acc[mi][ni][j], ss);
                ss += __shfl_xor(ss, 1); ss += __shfl_xor(ss, 2);
                ss += __shfl_xor(ss, 4); ss += __shfl_xor(ss, 8);
                float rr = rsqrtf(ss * (1.f / 64.f) + 1e-6f);
                const float* fb = freqs + (long)(t & (S_ - 1)) * 64;
                __hip_bfloat16* orow = outp + (long)t * tstride + cbase;
#pragma unroll
                for (int ni = 0; ni < 4; ++ni) {
                    float xv = acc[mi][ni][j] * rr * wv4[ni];
                    float pp = __shfl_xor(xv, 1);
                    float cc = fb[fo[ni]], sn = fb[fo[ni] + 1];
                    float y = par ? fmaf(pp, sn, xv * cc) : fmaf(xv, cc, -(pp * sn));
                    orow[ni * 16 + col_l] = __float2bfloat16(y);
                }
            }
        }
    } else {
        int kvv = (gbase - VOFF) >> 6;
#pragma unroll
        for (int mi = 0; mi < 4; ++mi) {
#pragma unroll
            for (int j = 0; j < 4; ++j) {
                int t = (int)m0 + wr * 64 + mi * 16 + kq * 4 + j;
                int bb = t >> 11, st = t & (S_ - 1);
                __hip_bfloat16* vcol = vout + ((long)(bb * KV_ + kvv) * 64) * S_ + st;
#pragma unroll
                for (int ni = 0; ni < 4; ++ni)
                    vcol[(long)(ni * 16 + col_l) * S_] = __float2bfloat16(acc[mi][ni][j]);
            }
        }
    }
}

// ---------------- NT GEMM, 128x64 tile (out-projection), triple-buffer single-barrier ----
__global__ __launch_bounds__(256) void gemm_bt_n64(const short* __restrict__ A,
                                                   const short* __restrict__ Bm,
                                                   float* __restrict__ C,
                                                   int M, int N, int K) {
    __shared__ __align__(16) short As[3][128 * 32];
    __shared__ __align__(16) short Bs[3][64 * 32];
    int tid = threadIdx.x;
    int wid = tid >> 6, lane = tid & 63;
    int wr = wid >> 1, wc = wid & 1;
    int r = lane & 15, kq = lane >> 4;

    int nwg = gridDim.x * gridDim.y;
    int orig = blockIdx.y * gridDim.x + blockIdx.x;
    int wg = (orig & 7) * (nwg >> 3) + (orig >> 3);
    int bx = wg % gridDim.x, by = wg / gridDim.x;

    long m0 = (long)by * 128;
    long n0 = (long)bx * 64;

    const short* gA0 = A + (m0 + (tid >> 2)) * (long)K + (tid & 3) * 8;
    const short* gA1 = A + (m0 + 64 + (tid >> 2)) * (long)K + (tid & 3) * 8;
    const short* gB0 = Bm + (n0 + (tid >> 2)) * (long)K + (tid & 3) * 8;

    auto stage = [&](int buf, int k0) {
        gload_lds16(gA0 + k0, &As[buf][wid * 512]);
        gload_lds16(gA1 + k0, &As[buf][2048 + wid * 512]);
        gload_lds16(gB0 + k0, &Bs[buf][wid * 512]);
    };

    floatx4 acc[4][2];
#pragma unroll
    for (int i = 0; i < 4; ++i)
#pragma unroll
        for (int j = 0; j < 2; ++j) acc[i][j] = {0.f, 0.f, 0.f, 0.f};

    int nt = K >> 5;
    stage(0, 0);
    if (nt > 1) stage(1, 32);
    int bk = 0;
    for (int t = 0; t < nt; ++t) {
        if (t + 1 < nt) asm volatile("s_waitcnt vmcnt(3)" ::: "memory");
        else            asm volatile("s_waitcnt vmcnt(0)" ::: "memory");
        __builtin_amdgcn_sched_barrier(0);
        __builtin_amdgcn_s_barrier();
        if (t + 2 < nt) {
            int bk2 = bk + 2; if (bk2 >= 3) bk2 -= 3;
            stage(bk2, (t + 2) << 5);
        }
        short8 a[4], b[2];
#pragma unroll
        for (int mi = 0; mi < 4; ++mi)
            a[mi] = *(const short8*)&As[bk][(wr * 64 + mi * 16 + r) * 32 + kq * 8];
#pragma unroll
        for (int ni = 0; ni < 2; ++ni)
            b[ni] = *(const short8*)&Bs[bk][(wc * 32 + ni * 16 + r) * 32 + kq * 8];
#pragma unroll
        for (int mi = 0; mi < 4; ++mi)
#pragma unroll
            for (int ni = 0; ni < 2; ++ni)
                acc[mi][ni] = __builtin_amdgcn_mfma_f32_16x16x32_bf16(
                    a[mi], b[ni], acc[mi][ni], 0, 0, 0);
        bk = (bk == 2) ? 0 : bk + 1;
    }
    int col_l = lane & 15, row_l = (lane >> 4) * 4;
#pragma unroll
    for (int mi = 0; mi < 4; ++mi)
#pragma unroll
        for (int ni = 0; ni < 2; ++ni) {
            long col = n0 + wc * 32 + ni * 16 + col_l;
            long row0 = m0 + wr * 64 + mi * 16 + row_l;
#pragma unroll
            for (int j = 0; j < 4; ++j)
                C[(row0 + j) * N + col] = acc[mi][ni][j];
        }
}

// ---------------- differential causal attention: paired-tile loop (r17/r18, passed) ------
__global__ __launch_bounds__(512, 4) void attn_kernel(const short* __restrict__ qb,
                                                      const short* __restrict__ kbuf,
                                                      const short* __restrict__ vtb,
                                                      __hip_bfloat16* __restrict__ ob,
                                                      unsigned* __restrict__ part,
                                                      float* __restrict__ lpart,
                                                      const float* __restrict__ lam_p) {
    __shared__ __align__(16) short Ks[4][32][128];
    __shared__ __align__(16) short Vt[4][64][40];

    int tid = threadIdx.x, w = tid >> 6, lane = tid & 63;
    int raw = (int)blockIdx.x;
    int xcd = raw & 7;
    int kv = xcd & 3, b = xcd >> 2;
    int i5 = raw >> 3;                  // [0,64)
    int x = i5 & 15, hh = i5 >> 4;      // x: pair+e, hh: head-in-group
    int h = kv * G_ + hh;
    int p = x >> 1, e = x & 1;
    int qtA = p, qtB = 15 - p;          // 128-row q-tiles
    int r = lane & 15, kq = lane >> 4;
    bool w4 = (w < 4);
    float lam = lam_p[0];

    floatx4 acc[2][4];
    floatx4 accl[2];
    short8 qa[2][2];

    const short* vbase = vtb + (long)(b * KV_ + kv) * 64 * S_;
    const float c1 = 0.18033688f, nc4 = -3.7570e-7f, zoff = -17.3123405f;
    const short one_bf = (short)0x3F80;
    short8 ones8 = {one_bf, one_bf, one_bf, one_bf, one_bf, one_bf, one_bf, one_bf};

    int krow0 = tid >> 4, kcs0 = ((tid & 15) ^ (krow0 & 7)) * 8;
    const short* kgb = kbuf + ((long)b * S_ * KV_ + kv) * 128;
    int vd = (tid >> 2) & 63, vch = tid & 3;   // V chunk within a 64x64 tile (per wave-half)
    int vsel = w4 ? 0 : 1;                     // which tile of the pair this wave stages

    auto issueK = [&](int buf, int ki) {
        long rb = (long)(ki * 32) * (KV_ * 128);
        gload_lds16(kgb + rb + (long)krow0 * (KV_ * 128) + kcs0, &Ks[buf][0][0] + w * 512);
    };
    auto loadV = [&](int kb) {
        return *(const short8*)(vbase + (long)vd * S_ + kb + vch * 8);
    };

    auto reset_acc = [&]() {
#pragma unroll
        for (int m = 0; m < 2; ++m) {
            accl[m] = {0.f, 0.f, 0.f, 0.f};
#pragma unroll
            for (int dt = 0; dt < 4; ++dt) acc[m][dt] = {0.f, 0.f, 0.f, 0.f};
        }
    };
    auto load_q = [&](int q0) {
        const short* qrow = qb + ((long)(b * S_ + q0 + r) * H_ + h) * 128;
        qa[0][0] = *(const short8*)(qrow + kq * 8);
        qa[0][1] = *(const short8*)(qrow + 32 + kq * 8);
        qa[1][0] = *(const short8*)(qrow + 64 + kq * 8);
        qa[1][1] = *(const short8*)(qrow + 96 + kq * 8);
    };

    auto tile_compute = [&](int bk, int cv, int kb, int q0, bool domask) {
        int rel = q0 + r - kb;
        short8 vb[4];
#pragma unroll
        for (int dt = 0; dt < 4; ++dt) {
            const short* vrow = &Vt[cv][dt * 16 + r][0];
            int2v lo = *(const int2v*)(vrow + 4 * kq);
            int2v hi = *(const int2v*)(vrow + 16 + 4 * kq);
            vb[dt] = __builtin_bit_cast(short8, int4v{lo[0], lo[1], hi[0], hi[1]});
        }
#pragma unroll
        for (int m = 0; m < 2; ++m) {
            floatx4 sacc[2];
            __builtin_amdgcn_s_setprio(1);
#pragma unroll
            for (int nt = 0; nt < 2; ++nt) {
                sacc[nt] = {0.f, 0.f, 0.f, 0.f};
                const short* row = &Ks[bk][nt * 16 + r][0];
                short8 a0 = *(const short8*)(row + (((m * 8) + kq) ^ (r & 7)) * 8);
                short8 a1 = *(const short8*)(row + (((m * 8) + 4 + kq) ^ (r & 7)) * 8);
                sacc[nt] = __builtin_amdgcn_mfma_f32_16x16x32_bf16(a0, qa[m][0], sacc[nt], 0, 0, 0);
                sacc[nt] = __builtin_amdgcn_mfma_f32_16x16x32_bf16(a1, qa[m][1], sacc[nt], 0, 0, 0);
            }
            __builtin_amdgcn_s_setprio(0);
            float pv[2][4];
#pragma unroll
            for (int nt = 0; nt < 2; ++nt)
#pragma unroll
                for (int j = 0; j < 4; ++j) {
                    float rawv = sacc[nt][j];
                    float r2 = rawv * rawv;
                    float z = fmaf(rawv, fmaf(r2, nc4, c1), zoff);
                    pv[nt][j] = __builtin_amdgcn_exp2f(z);
                }
            if (domask) {
#pragma unroll
                for (int nt = 0; nt < 2; ++nt)
#pragma unroll
                    for (int j = 0; j < 4; ++j)
                        if (nt * 16 + kq * 4 + j > rel) pv[nt][j] = 0.f;
            }
            int d0 = cvt_pk_bf16(pv[0][0], pv[0][1]);
            int d1 = cvt_pk_bf16(pv[0][2], pv[0][3]);
            int d2 = cvt_pk_bf16(pv[1][0], pv[1][1]);
            int d3 = cvt_pk_bf16(pv[1][2], pv[1][3]);
            short8 pa8 = __builtin_bit_cast(short8, int4v{d0, d1, d2, d3});
            __builtin_amdgcn_s_setprio(1);
#pragma unroll
            for (int dt = 0; dt < 4; ++dt)
                acc[m][dt] = __builtin_amdgcn_mfma_f32_16x16x32_bf16(
                    pa8, vb[dt], acc[m][dt], 0, 0, 0);
            accl[m] = __builtin_amdgcn_mfma_f32_16x16x32_bf16(pa8, ones8, accl[m], 0, 0, 0);
            __builtin_amdgcn_s_setprio(0);
        }
    };

    // run over 32-k-tiles [ki0, ki1), two tiles per barrier
    auto run = [&](int qt, int ki0, int ki1, bool diag) {
        int q0 = qt * 128 + w * 16;
        load_q(q0);
        reset_acc();
        int nseg = ki1 - ki0;
        issueK(0, ki0);
        if (nseg > 1) issueK(1, ki0 + 1);
        short8 rva = {};
        if (vsel < nseg) rva = loadV((ki0 + vsel) * 32);
        int ii = 0;
        for (; ii + 1 < nseg; ii += 2) {
            int vb0 = 2 * ((ii >> 1) & 1);        // V bufs {0,1} or {2,3}
            *(short8*)&Vt[vb0 + vsel][vd][vch * 8] = rva;
            asm volatile("s_waitcnt vmcnt(0)" ::: "memory");
            asm volatile("s_waitcnt lgkmcnt(0)" ::: "memory");
            __builtin_amdgcn_sched_barrier(0);
            __builtin_amdgcn_s_barrier();
            if (ii + 2 < nseg) {                   // issue pair p+1 (after barrier: race-free)
                issueK((ii + 2) & 3, ki0 + ii + 2);
                if (ii + 3 < nseg) issueK((ii + 3) & 3, ki0 + ii + 3);
                int nxt = ii + 2 + vsel;
                if (nxt < nseg) rva = loadV((ki0 + nxt) * 32);
            }
            int ki = ki0 + ii;
            tile_compute(ii & 3, vb0, ki * 32, q0, diag && (ki >= 4 * qt));
            tile_compute((ii + 1) & 3, vb0 + 1, (ki + 1) * 32, q0,
                         diag && (ki + 1 >= 4 * qt));
        }
        if (ii < nseg) {                           // odd tail (not hit: all nseg even)
            int vb0 = 2 * ((ii >> 1) & 1);
            if (w4) *(short8*)&Vt[vb0][vd][vch * 8] = rva;
            asm volatile("s_waitcnt vmcnt(0)" ::: "memory");
            asm volatile("s_waitcnt lgkmcnt(0)" ::: "memory");
            __builtin_amdgcn_sched_barrier(0);
            __builtin_amdgcn_s_barrier();
            int ki = ki0 + ii;
            tile_compute(ii & 3, vb0, ki * 32, q0, diag && (ki >= 4 * qt));
        }
        __builtin_amdgcn_s_barrier();   // protect LDS reuse across runs
    };

    if (e == 0) {
        run(qtA, 0, 4 * qtA + 4, true);
        {
            int q0 = qtA * 128 + w * 16;
#pragma unroll
            for (int j = 0; j < 4; ++j) {
                float i1 = 1.f / accl[0][j];
                float i2 = lam / accl[1][j];
                int qr = q0 + kq * 4 + j;
                __hip_bfloat16* orow = ob + ((long)(b * S_ + qr) * H_ + h) * 64;
#pragma unroll
                for (int dt = 0; dt < 4; ++dt) {
                    float val = acc[0][dt][j] * i1 - acc[1][dt][j] * i2;
                    orow[dt * 16 + r] = __float2bfloat16(val);
                }
            }
        }
        run(qtB, 0, 30 - 4 * p, false);             // k-prefix of qtB
    } else {
        run(qtB, 30 - 4 * p, 64 - 4 * p, true);     // k-suffix incl diagonal
    }

    // write packed partial: slot = (b*H+h)*8 + (qtB-8), half = e; dword = (m0,m1) bf16x2
    {
        long slot = (long)(b * H_ + h) * 8 + (qtB - 8);
        long base = (slot * 2 + e) * 8192L;
        int qloc = w * 16 + kq * 4;
#pragma unroll
        for (int dt = 0; dt < 4; ++dt)
#pragma unroll
            for (int j = 0; j < 4; ++j)
                part[base + (qloc + j) * 64 + dt * 16 + r] =
                    (unsigned)cvt_pk_bf16(acc[0][dt][j], acc[1][dt][j]);
        if (r == 0) {
#pragma unroll
            for (int m = 0; m < 2; ++m)
#pragma unroll
                for (int j = 0; j < 4; ++j)
                    lpart[((slot * 2 + e) * 2 + m) * 128 + qloc + j] = accl[m][j];
        }
    }
}

// ---------------- merge packed partials for qt128 in [8,16) ----------
__global__ __launch_bounds__(256) void attn_merge_kernel(const unsigned* __restrict__ part,
                                                         const float* __restrict__ lpart,
                                                         __hip_bfloat16* __restrict__ ob,
                                                         const float* __restrict__ lam_p) {
    long sid = blockIdx.x;               // (b*H+h)*8 + (qt-8), 256 slots
    int t8 = sid & 7;
    int h = (sid >> 3) & (H_ - 1);
    int b = (int)(sid >> 7);
    int qt = 8 + t8;
    float lam = lam_p[0];
    const unsigned* p0 = part + sid * 2 * 8192L;
    const unsigned* p1 = p0 + 8192;
    const float* l0 = lpart + sid * 512L;    // e=0: m0 at +0, m1 at +128
    const float* l1 = l0 + 256;              // e=1
    int tid = threadIdx.x;
#pragma unroll
    for (int i = 0; i < 32; ++i) {
        int idx = i * 256 + tid;
        int q = idx >> 6, d = idx & 63;
        unsigned u0 = p0[q * 64 + d], u1 = p1[q * 64 + d];
        float a1 = bf16lo(u0) + bf16lo(u1);
        float a2 = bf16hi(u0) + bf16hi(u1);
        float L1 = l0[q] + l1[q];
        float L2 = l0[128 + q] + l1[128 + q];
        float val = a1 / L1 - lam * (a2 / L2);
        ob[((long)(b * S_ + qt * 128 + q) * H_ + h) * 64 + d] = __float2bfloat16(val);
    }
}

// ---------------- launch ----------------
extern "C" void kernel_launch(void* const* d_in, const int* in_sizes, int n_in,
                              void* d_out, int out_size, void* d_ws, size_t ws_size,
                              hipStream_t stream) {
    const float* x     = (const float*)d_in[0];
    const float* freqs = (const float*)d_in[1];
    const float* wq    = (const float*)d_in[2];
    const float* wk    = (const float*)d_in[3];
    const float* wv    = (const float*)d_in[4];
    const float* wo    = (const float*)d_in[5];
    const float* qnw   = (const float*)d_in[6];
    const float* knw   = (const float*)d_in[7];
    const float* lam   = (const float*)d_in[8];
    float* out = (float*)d_out;

    const int T = B_ * S_;
    char* ws = (char*)d_ws;
    size_t off = 0;
    auto alloc = [&](size_t bytes) {
        void* p = ws + off;
        off += (bytes + 255) & ~(size_t)255;
        return p;
    };
    __hip_bfloat16* xb   = (__hip_bfloat16*)alloc((size_t)T * D_ * 2);
    __hip_bfloat16* wcat = (__hip_bfloat16*)alloc((size_t)NCAT * D_ * 2);
    __hip_bfloat16* wob  = (__hip_bfloat16*)alloc((size_t)D_ * D_ * 2);
    __hip_bfloat16* qb16 = (__hip_bfloat16*)alloc((size_t)T * 2 * H_ * HD_ * 2);
    __hip_bfloat16* kb16 = (__hip_bfloat16*)alloc((size_t)T * 2 * KV_ * HD_ * 2);
    __hip_bfloat16* vT   = (__hip_bfloat16*)alloc((size_t)B_ * KV_ * HD_ * S_ * 2);
    unsigned* part = (unsigned*)alloc((size_t)256 * 2 * 8192 * 4);
    float* lpart   = (float*)alloc((size_t)256 * 2 * 2 * 128 * 4);
    __hip_bfloat16* aob  = xb;   // xb dead after QKV GEMM; same size

    // fused cvt: x, wq, wk, wv, wo (wcat segments are contiguous)
    cvt5_kernel<<<dim3(2048, 5), 256, 0, stream>>>(
        x, wq, wk, wv, wo,
        xb, wcat, wcat + (size_t)2 * H_ * HD_ * D_,
        wcat + (size_t)(2 * H_ * HD_ + 2 * KV_ * HD_) * D_, wob,
        T * D_, 2 * H_ * HD_ * D_, 2 * KV_ * HD_ * D_, KV_ * HD_ * D_, D_ * D_);

    // fused QKV projection + RMSNorm + RoPE + V-transpose
    gemm_qkv_fused<<<dim3(NCAT / 128, T / 128), 256, 0, stream>>>(
        (const short*)xb, (const short*)wcat, qb16, kb16, vT,
        freqs, qnw, knw, T, NCAT, D_);

    // differential causal attention + merge
    attn_kernel<<<512, 512, 0, stream>>>(
        (const short*)qb16, (const short*)kb16, (const short*)vT, aob, part, lpart, lam);
    attn_merge_kernel<<<256, 256, 0, stream>>>(part, lpart, aob, lam);

    // output projection -> f32 (128x64 tiles, 512 blocks = 2/CU)
    gemm_bt_n64<<<dim3(D_ / 64, T / 128), 256, 0, stream>>>(
        (const short*)aob, (const short*)wob, out, T, D_, D_);
}

// Round 20
// 150.838 us; speedup vs baseline: 1.4045x; 1.0176x over previous
//
#include <hip/hip_runtime.h>
#include <hip/hip_bf16.h>

#define B_ 2
#define S_ 2048
#define D_ 1024
#define H_ 16
#define KV_ 4
#define HD_ 64
#define G_ (H_ / KV_)
#define NCAT 2816          // 2*H*HD + 2*KV*HD + KV*HD
#define VOFF 2560          // col offset of V block in fused QKV output

typedef __attribute__((ext_vector_type(8))) short short8;
typedef __attribute__((ext_vector_type(4))) short short4v;
typedef __attribute__((ext_vector_type(2))) int int2v;
typedef __attribute__((ext_vector_type(4))) int int4v;
typedef __attribute__((ext_vector_type(4))) float floatx4;

using gvoid_p = const __attribute__((address_space(1))) void*;
using lvoid_p = __attribute__((address_space(3))) void*;

__device__ inline void gload_lds16(const short* g, short* l) {
    __builtin_amdgcn_global_load_lds((gvoid_p)(const void*)g, (lvoid_p)(void*)l, 16, 0, 0);
}

__device__ inline int cvt_pk_bf16(float lo, float hi) {
    int r;
    asm volatile("v_cvt_pk_bf16_f32 %0, %1, %2" : "=v"(r) : "v"(lo), "v"(hi));
    return r;
}

__device__ inline float bf16lo(unsigned u) {
    return __builtin_bit_cast(float, u << 16);
}
__device__ inline float bf16hi(unsigned u) {
    return __builtin_bit_cast(float, u & 0xffff0000u);
}

// ---------------- fused fp32 -> bf16 convert (5 segments, float4 vectorized) -------------
__global__ void cvt5_kernel(const float* s0, const float* s1, const float* s2,
                            const float* s3, const float* s4,
                            __hip_bfloat16* d0, __hip_bfloat16* d1, __hip_bfloat16* d2,
                            __hip_bfloat16* d3, __hip_bfloat16* d4,
                            int n0, int n1, int n2, int n3, int n4) {
    const float* s; __hip_bfloat16* d; int n;
    switch (blockIdx.y) {
        case 0: s = s0; d = d0; n = n0; break;
        case 1: s = s1; d = d1; n = n1; break;
        case 2: s = s2; d = d2; n = n2; break;
        case 3: s = s3; d = d3; n = n3; break;
        default: s = s4; d = d4; n = n4; break;
    }
    int nv = n >> 2;
    for (int i = blockIdx.x * blockDim.x + threadIdx.x; i < nv;
         i += gridDim.x * blockDim.x) {
        floatx4 v = ((const floatx4*)s)[i];
        short4v o;
#pragma unroll
        for (int e = 0; e < 4; ++e) {
            __hip_bfloat16 hh = __float2bfloat16(v[e]);
            o[e] = __builtin_bit_cast(short, hh);
        }
        ((short4v*)d)[i] = o;
    }
}

// ---------------- QKV GEMM with FUSED RMSNorm+RoPE epilogue (r19, passed) ----------------
__global__ __launch_bounds__(256) void gemm_qkv_fused(const short* __restrict__ A,
                                                      const short* __restrict__ Bm,
                                                      __hip_bfloat16* __restrict__ qout,
                                                      __hip_bfloat16* __restrict__ kout,
                                                      __hip_bfloat16* __restrict__ vout,
                                                      const float* __restrict__ freqs,
                                                      const float* __restrict__ qnw,
                                                      const float* __restrict__ knw,
                                                      int M, int N, int K) {
    __shared__ __align__(16) short As[3][128 * 32];
    __shared__ __align__(16) short Bs[3][128 * 32];
    int tid = threadIdx.x;
    int wid = tid >> 6, lane = tid & 63;
    int wr = wid >> 1, wc = wid & 1;
    int r = lane & 15, kq = lane >> 4;

    int nwg = gridDim.x * gridDim.y;
    int orig = blockIdx.y * gridDim.x + blockIdx.x;
    int wg = (orig & 7) * (nwg >> 3) + (orig >> 3);
    int bx = wg % gridDim.x, by = wg / gridDim.x;

    long m0 = (long)by * 128;
    long n0 = (long)bx * 128;

    const short* gA0 = A + (m0 + (tid >> 2)) * (long)K + (tid & 3) * 8;
    const short* gA1 = A + (m0 + 64 + (tid >> 2)) * (long)K + (tid & 3) * 8;
    const short* gB0 = Bm + (n0 + (tid >> 2)) * (long)K + (tid & 3) * 8;
    const short* gB1 = Bm + (n0 + 64 + (tid >> 2)) * (long)K + (tid & 3) * 8;

    auto stage = [&](int buf, int k0) {
        gload_lds16(gA0 + k0, &As[buf][wid * 512]);
        gload_lds16(gA1 + k0, &As[buf][2048 + wid * 512]);
        gload_lds16(gB0 + k0, &Bs[buf][wid * 512]);
        gload_lds16(gB1 + k0, &Bs[buf][2048 + wid * 512]);
    };

    floatx4 acc[4][4];
#pragma unroll
    for (int i = 0; i < 4; ++i)
#pragma unroll
        for (int j = 0; j < 4; ++j) acc[i][j] = {0.f, 0.f, 0.f, 0.f};

    int nt = K >> 5;
    stage(0, 0);
    if (nt > 1) stage(1, 32);
    int bk = 0;
    for (int t = 0; t < nt; ++t) {
        if (t + 1 < nt) asm volatile("s_waitcnt vmcnt(4)" ::: "memory");
        else            asm volatile("s_waitcnt vmcnt(0)" ::: "memory");
        __builtin_amdgcn_sched_barrier(0);
        __builtin_amdgcn_s_barrier();
        if (t + 2 < nt) {
            int bk2 = bk + 2; if (bk2 >= 3) bk2 -= 3;
            stage(bk2, (t + 2) << 5);
        }
        short8 a[4], b[4];
#pragma unroll
        for (int mi = 0; mi < 4; ++mi)
            a[mi] = *(const short8*)&As[bk][(wr * 64 + mi * 16 + r) * 32 + kq * 8];
#pragma unroll
        for (int ni = 0; ni < 4; ++ni)
            b[ni] = *(const short8*)&Bs[bk][(wc * 64 + ni * 16 + r) * 32 + kq * 8];
#pragma unroll
        for (int mi = 0; mi < 4; ++mi)
#pragma unroll
            for (int ni = 0; ni < 4; ++ni)
                acc[mi][ni] = __builtin_amdgcn_mfma_f32_16x16x32_bf16(
                    a[mi], b[ni], acc[mi][ni], 0, 0, 0);
        bk = (bk == 2) ? 0 : bk + 1;
    }

    // ---------- fused epilogue ----------
    int col_l = lane & 15;
    int gbase = (int)n0 + wc * 64;
    int par = col_l & 1;
    if (gbase < VOFF) {
        const float* wnorm = (gbase < 2048) ? qnw : knw;
        float wv4[4];
        int fo[4];
#pragma unroll
        for (int ni = 0; ni < 4; ++ni) {
            wv4[ni] = wnorm[ni * 16 + col_l];
            fo[ni] = ni * 16 + (col_l >> 1) * 2;
        }
        __hip_bfloat16* outp;
        long tstride;
        int cbase;
        if (gbase < 2048) { outp = qout; tstride = 2048; cbase = gbase; }
        else              { outp = kout; tstride = 512;  cbase = gbase - 2048; }
#pragma unroll
        for (int mi = 0; mi < 4; ++mi) {
#pragma unroll
            for (int j = 0; j < 4; ++j) {
                int t = (int)m0 + wr * 64 + mi * 16 + kq * 4 + j;
                float ss = 0.f;
#pragma unroll
                for (int ni = 0; ni < 4; ++ni)
                    ss = fmaf(acc[mi][ni][j], acc[mi][ni][j], ss);
                ss += __shfl_xor(ss, 1); ss += __shfl_xor(ss, 2);
                ss += __shfl_xor(ss, 4); ss += __shfl_xor(ss, 8);
                float rr = rsqrtf(ss * (1.f / 64.f) + 1e-6f);
                const float* fb = freqs + (long)(t & (S_ - 1)) * 64;
                __hip_bfloat16* orow = outp + (long)t * tstride + cbase;
#pragma unroll
                for (int ni = 0; ni < 4; ++ni) {
                    float xv = acc[mi][ni][j] * rr * wv4[ni];
                    float pp = __shfl_xor(xv, 1);
                    float cc = fb[fo[ni]], sn = fb[fo[ni] + 1];
                    float y = par ? fmaf(pp, sn, xv * cc) : fmaf(xv, cc, -(pp * sn));
                    orow[ni * 16 + col_l] = __float2bfloat16(y);
                }
            }
        }
    } else {
        int kvv = (gbase - VOFF) >> 6;
#pragma unroll
        for (int mi = 0; mi < 4; ++mi) {
#pragma unroll
            for (int j = 0; j < 4; ++j) {
                int t = (int)m0 + wr * 64 + mi * 16 + kq * 4 + j;
                int bb = t >> 11, st = t & (S_ - 1);
                __hip_bfloat16* vcol = vout + ((long)(bb * KV_ + kvv) * 64) * S_ + st;
#pragma unroll
                for (int ni = 0; ni < 4; ++ni)
                    vcol[(long)(ni * 16 + col_l) * S_] = __float2bfloat16(acc[mi][ni][j]);
            }
        }
    }
}

// ---------------- NT GEMM, 128x64 tile (out-projection), triple-buffer single-barrier ----
__global__ __launch_bounds__(256) void gemm_bt_n64(const short* __restrict__ A,
                                                   const short* __restrict__ Bm,
                                                   float* __restrict__ C,
                                                   int M, int N, int K) {
    __shared__ __align__(16) short As[3][128 * 32];
    __shared__ __align__(16) short Bs[3][64 * 32];
    int tid = threadIdx.x;
    int wid = tid >> 6, lane = tid & 63;
    int wr = wid >> 1, wc = wid & 1;
    int r = lane & 15, kq = lane >> 4;

    int nwg = gridDim.x * gridDim.y;
    int orig = blockIdx.y * gridDim.x + blockIdx.x;
    int wg = (orig & 7) * (nwg >> 3) + (orig >> 3);
    int bx = wg % gridDim.x, by = wg / gridDim.x;

    long m0 = (long)by * 128;
    long n0 = (long)bx * 64;

    const short* gA0 = A + (m0 + (tid >> 2)) * (long)K + (tid & 3) * 8;
    const short* gA1 = A + (m0 + 64 + (tid >> 2)) * (long)K + (tid & 3) * 8;
    const short* gB0 = Bm + (n0 + (tid >> 2)) * (long)K + (tid & 3) * 8;

    auto stage = [&](int buf, int k0) {
        gload_lds16(gA0 + k0, &As[buf][wid * 512]);
        gload_lds16(gA1 + k0, &As[buf][2048 + wid * 512]);
        gload_lds16(gB0 + k0, &Bs[buf][wid * 512]);
    };

    floatx4 acc[4][2];
#pragma unroll
    for (int i = 0; i < 4; ++i)
#pragma unroll
        for (int j = 0; j < 2; ++j) acc[i][j] = {0.f, 0.f, 0.f, 0.f};

    int nt = K >> 5;
    stage(0, 0);
    if (nt > 1) stage(1, 32);
    int bk = 0;
    for (int t = 0; t < nt; ++t) {
        if (t + 1 < nt) asm volatile("s_waitcnt vmcnt(3)" ::: "memory");
        else            asm volatile("s_waitcnt vmcnt(0)" ::: "memory");
        __builtin_amdgcn_sched_barrier(0);
        __builtin_amdgcn_s_barrier();
        if (t + 2 < nt) {
            int bk2 = bk + 2; if (bk2 >= 3) bk2 -= 3;
            stage(bk2, (t + 2) << 5);
        }
        short8 a[4], b[2];
#pragma unroll
        for (int mi = 0; mi < 4; ++mi)
            a[mi] = *(const short8*)&As[bk][(wr * 64 + mi * 16 + r) * 32 + kq * 8];
#pragma unroll
        for (int ni = 0; ni < 2; ++ni)
            b[ni] = *(const short8*)&Bs[bk][(wc * 32 + ni * 16 + r) * 32 + kq * 8];
#pragma unroll
        for (int mi = 0; mi < 4; ++mi)
#pragma unroll
            for (int ni = 0; ni < 2; ++ni)
                acc[mi][ni] = __builtin_amdgcn_mfma_f32_16x16x32_bf16(
                    a[mi], b[ni], acc[mi][ni], 0, 0, 0);
        bk = (bk == 2) ? 0 : bk + 1;
    }
    int col_l = lane & 15, row_l = (lane >> 4) * 4;
#pragma unroll
    for (int mi = 0; mi < 4; ++mi)
#pragma unroll
        for (int ni = 0; ni < 2; ++ni) {
            long col = n0 + wc * 32 + ni * 16 + col_l;
            long row0 = m0 + wr * 64 + mi * 16 + row_l;
#pragma unroll
            for (int j = 0; j < 4; ++j)
                C[(row0 + j) * N + col] = acc[mi][ni][j];
        }
}

// ---------------- differential causal attention: paired-tile loop (r17-r19, passed) ------
__global__ __launch_bounds__(512, 4) void attn_kernel(const short* __restrict__ qb,
                                                      const short* __restrict__ kbuf,
                                                      const short* __restrict__ vtb,
                                                      __hip_bfloat16* __restrict__ ob,
                                                      unsigned* __restrict__ part,
                                                      float* __restrict__ lpart,
                                                      const float* __restrict__ lam_p) {
    __shared__ __align__(16) short Ks[4][32][128];
    __shared__ __align__(16) short Vt[4][64][40];

    int tid = threadIdx.x, w = tid >> 6, lane = tid & 63;
    int raw = (int)blockIdx.x;
    int xcd = raw & 7;
    int kv = xcd & 3, b = xcd >> 2;
    int i5 = raw >> 3;                  // [0,64)
    int x = i5 & 15, hh = i5 >> 4;      // x: pair+e, hh: head-in-group
    int h = kv * G_ + hh;
    int p = x >> 1, e = x & 1;
    int qtA = p, qtB = 15 - p;          // 128-row q-tiles
    int r = lane & 15, kq = lane >> 4;
    bool w4 = (w < 4);
    float lam = lam_p[0];

    floatx4 acc[2][4];
    floatx4 accl[2];
    short8 qa[2][2];

    const short* vbase = vtb + (long)(b * KV_ + kv) * 64 * S_;
    const float c1 = 0.18033688f, nc4 = -3.7570e-7f, zoff = -17.3123405f;
    const short one_bf = (short)0x3F80;
    short8 ones8 = {one_bf, one_bf, one_bf, one_bf, one_bf, one_bf, one_bf, one_bf};

    int krow0 = tid >> 4, kcs0 = ((tid & 15) ^ (krow0 & 7)) * 8;
    const short* kgb = kbuf + ((long)b * S_ * KV_ + kv) * 128;
    int vd = (tid >> 2) & 63, vch = tid & 3;   // V chunk within a 64x64 tile (per wave-half)
    int vsel = w4 ? 0 : 1;                     // which tile of the pair this wave stages

    auto issueK = [&](int buf, int ki) {
        long rb = (long)(ki * 32) * (KV_ * 128);
        gload_lds16(kgb + rb + (long)krow0 * (KV_ * 128) + kcs0, &Ks[buf][0][0] + w * 512);
    };
    auto loadV = [&](int kb) {
        return *(const short8*)(vbase + (long)vd * S_ + kb + vch * 8);
    };

    auto reset_acc = [&]() {
#pragma unroll
        for (int m = 0; m < 2; ++m) {
            accl[m] = {0.f, 0.f, 0.f, 0.f};
#pragma unroll
            for (int dt = 0; dt < 4; ++dt) acc[m][dt] = {0.f, 0.f, 0.f, 0.f};
        }
    };
    auto load_q = [&](int q0) {
        const short* qrow = qb + ((long)(b * S_ + q0 + r) * H_ + h) * 128;
        qa[0][0] = *(const short8*)(qrow + kq * 8);
        qa[0][1] = *(const short8*)(qrow + 32 + kq * 8);
        qa[1][0] = *(const short8*)(qrow + 64 + kq * 8);
        qa[1][1] = *(const short8*)(qrow + 96 + kq * 8);
    };

    auto tile_compute = [&](int bk, int cv, int kb, int q0, bool domask) {
        int rel = q0 + r - kb;
        short8 vb[4];
#pragma unroll
        for (int dt = 0; dt < 4; ++dt) {
            const short* vrow = &Vt[cv][dt * 16 + r][0];
            int2v lo = *(const int2v*)(vrow + 4 * kq);
            int2v hi = *(const int2v*)(vrow + 16 + 4 * kq);
            vb[dt] = __builtin_bit_cast(short8, int4v{lo[0], lo[1], hi[0], hi[1]});
        }
#pragma unroll
        for (int m = 0; m < 2; ++m) {
            floatx4 sacc[2];
            __builtin_amdgcn_s_setprio(1);
#pragma unroll
            for (int nt = 0; nt < 2; ++nt) {
                sacc[nt] = {0.f, 0.f, 0.f, 0.f};
                const short* row = &Ks[bk][nt * 16 + r][0];
                short8 a0 = *(const short8*)(row + (((m * 8) + kq) ^ (r & 7)) * 8);
                short8 a1 = *(const short8*)(row + (((m * 8) + 4 + kq) ^ (r & 7)) * 8);
                sacc[nt] = __builtin_amdgcn_mfma_f32_16x16x32_bf16(a0, qa[m][0], sacc[nt], 0, 0, 0);
                sacc[nt] = __builtin_amdgcn_mfma_f32_16x16x32_bf16(a1, qa[m][1], sacc[nt], 0, 0, 0);
            }
            __builtin_amdgcn_s_setprio(0);
            float pv[2][4];
#pragma unroll
            for (int nt = 0; nt < 2; ++nt)
#pragma unroll
                for (int j = 0; j < 4; ++j) {
                    float rawv = sacc[nt][j];
                    float r2 = rawv * rawv;
                    float z = fmaf(rawv, fmaf(r2, nc4, c1), zoff);
                    pv[nt][j] = __builtin_amdgcn_exp2f(z);
                }
            if (domask) {
#pragma unroll
                for (int nt = 0; nt < 2; ++nt)
#pragma unroll
                    for (int j = 0; j < 4; ++j)
                        if (nt * 16 + kq * 4 + j > rel) pv[nt][j] = 0.f;
            }
            int d0 = cvt_pk_bf16(pv[0][0], pv[0][1]);
            int d1 = cvt_pk_bf16(pv[0][2], pv[0][3]);
            int d2 = cvt_pk_bf16(pv[1][0], pv[1][1]);
            int d3 = cvt_pk_bf16(pv[1][2], pv[1][3]);
            short8 pa8 = __builtin_bit_cast(short8, int4v{d0, d1, d2, d3});
            __builtin_amdgcn_s_setprio(1);
#pragma unroll
            for (int dt = 0; dt < 4; ++dt)
                acc[m][dt] = __builtin_amdgcn_mfma_f32_16x16x32_bf16(
                    pa8, vb[dt], acc[m][dt], 0, 0, 0);
            accl[m] = __builtin_amdgcn_mfma_f32_16x16x32_bf16(pa8, ones8, accl[m], 0, 0, 0);
            __builtin_amdgcn_s_setprio(0);
        }
    };

    // run over 32-k-tiles [ki0, ki1), two tiles per barrier
    auto run = [&](int qt, int ki0, int ki1, bool diag) {
        int q0 = qt * 128 + w * 16;
        load_q(q0);
        reset_acc();
        int nseg = ki1 - ki0;
        issueK(0, ki0);
        if (nseg > 1) issueK(1, ki0 + 1);
        short8 rva = {};
        if (vsel < nseg) rva = loadV((ki0 + vsel) * 32);
        int ii = 0;
        for (; ii + 1 < nseg; ii += 2) {
            int vb0 = 2 * ((ii >> 1) & 1);        // V bufs {0,1} or {2,3}
            *(short8*)&Vt[vb0 + vsel][vd][vch * 8] = rva;
            asm volatile("s_waitcnt vmcnt(0)" ::: "memory");
            asm volatile("s_waitcnt lgkmcnt(0)" ::: "memory");
            __builtin_amdgcn_sched_barrier(0);
            __builtin_amdgcn_s_barrier();
            if (ii + 2 < nseg) {                   // issue pair p+1 (after barrier: race-free)
                issueK((ii + 2) & 3, ki0 + ii + 2);
                if (ii + 3 < nseg) issueK((ii + 3) & 3, ki0 + ii + 3);
                int nxt = ii + 2 + vsel;
                if (nxt < nseg) rva = loadV((ki0 + nxt) * 32);
            }
            int ki = ki0 + ii;
            tile_compute(ii & 3, vb0, ki * 32, q0, diag && (ki >= 4 * qt));
            tile_compute((ii + 1) & 3, vb0 + 1, (ki + 1) * 32, q0,
                         diag && (ki + 1 >= 4 * qt));
        }
        if (ii < nseg) {                           // odd tail (not hit: all nseg even)
            int vb0 = 2 * ((ii >> 1) & 1);
            if (w4) *(short8*)&Vt[vb0][vd][vch * 8] = rva;
            asm volatile("s_waitcnt vmcnt(0)" ::: "memory");
            asm volatile("s_waitcnt lgkmcnt(0)" ::: "memory");
            __builtin_amdgcn_sched_barrier(0);
            __builtin_amdgcn_s_barrier();
            int ki = ki0 + ii;
            tile_compute(ii & 3, vb0, ki * 32, q0, diag && (ki >= 4 * qt));
        }
        __builtin_amdgcn_s_barrier();   // protect LDS reuse across runs
    };

    if (e == 0) {
        run(qtA, 0, 4 * qtA + 4, true);
        {
            int q0 = qtA * 128 + w * 16;
#pragma unroll
            for (int j = 0; j < 4; ++j) {
                float i1 = 1.f / accl[0][j];
                float i2 = lam / accl[1][j];
                int qr = q0 + kq * 4 + j;
                __hip_bfloat16* orow = ob + ((long)(b * S_ + qr) * H_ + h) * 64;
#pragma unroll
                for (int dt = 0; dt < 4; ++dt) {
                    float val = acc[0][dt][j] * i1 - acc[1][dt][j] * i2;
                    orow[dt * 16 + r] = __float2bfloat16(val);
                }
            }
        }
        run(qtB, 0, 30 - 4 * p, false);             // k-prefix of qtB
    } else {
        run(qtB, 30 - 4 * p, 64 - 4 * p, true);     // k-suffix incl diagonal
    }

    // write packed partial: slot = (b*H+h)*8 + (qtB-8), half = e; dword = (m0,m1) bf16x2
    {
        long slot = (long)(b * H_ + h) * 8 + (qtB - 8);
        long base = (slot * 2 + e) * 8192L;
        int qloc = w * 16 + kq * 4;
#pragma unroll
        for (int dt = 0; dt < 4; ++dt)
#pragma unroll
            for (int j = 0; j < 4; ++j)
                part[base + (qloc + j) * 64 + dt * 16 + r] =
                    (unsigned)cvt_pk_bf16(acc[0][dt][j], acc[1][dt][j]);
        if (r == 0) {
#pragma unroll
            for (int m = 0; m < 2; ++m)
#pragma unroll
                for (int j = 0; j < 4; ++j)
                    lpart[((slot * 2 + e) * 2 + m) * 128 + qloc + j] = accl[m][j];
        }
    }
}

// ---------------- merge packed partials for qt128 in [8,16): 512 blocks, vectorized ------
// Grid 512 = 2 blocks per slot (q-halves); int4v loads (16B) + short4v stores (8B).
__global__ __launch_bounds__(256) void attn_merge_kernel(const unsigned* __restrict__ part,
                                                         const float* __restrict__ lpart,
                                                         __hip_bfloat16* __restrict__ ob,
                                                         const float* __restrict__ lam_p) {
    long sid = blockIdx.x >> 1;          // (b*H+h)*8 + (qt-8), 256 slots
    int half = blockIdx.x & 1;           // q in [half*64, half*64+64)
    int t8 = (int)(sid & 7);
    int h = (int)((sid >> 3) & (H_ - 1));
    int b = (int)(sid >> 7);
    int qt = 8 + t8;
    float lam = lam_p[0];
    const unsigned* p0 = part + sid * 2 * 8192L;
    const unsigned* p1 = p0 + 8192;
    const float* l0 = lpart + sid * 512L;    // e=0: m0 at +0, m1 at +128
    const float* l1 = l0 + 256;              // e=1
    int tid = threadIdx.x;
#pragma unroll
    for (int i = 0; i < 4; ++i) {
        int idx4 = i * 256 + tid;            // 1024 vec4 slots = 64 q x 16 d-quads
        int q = (idx4 >> 4) + half * 64;
        int d4 = (idx4 & 15) * 4;
        int4v u0 = *(const int4v*)&p0[q * 64 + d4];
        int4v u1 = *(const int4v*)&p1[q * 64 + d4];
        float iL1 = 1.f / (l0[q] + l1[q]);
        float iL2 = lam / (l0[128 + q] + l1[128 + q]);
        short4v o;
#pragma unroll
        for (int e2 = 0; e2 < 4; ++e2) {
            unsigned a = (unsigned)u0[e2], c = (unsigned)u1[e2];
            float a1 = bf16lo(a) + bf16lo(c);
            float a2 = bf16hi(a) + bf16hi(c);
            float val = a1 * iL1 - a2 * iL2;
            o[e2] = __builtin_bit_cast(short, __float2bfloat16(val));
        }
        *(short4v*)(ob + ((long)(b * S_ + qt * 128 + q) * H_ + h) * 64 + d4) = o;
    }
}

// ---------------- launch ----------------
extern "C" void kernel_launch(void* const* d_in, const int* in_sizes, int n_in,
                              void* d_out, int out_size, void* d_ws, size_t ws_size,
                              hipStream_t stream) {
    const float* x     = (const float*)d_in[0];
    const float* freqs = (const float*)d_in[1];
    const float* wq    = (const float*)d_in[2];
    const float* wk    = (const float*)d_in[3];
    const float* wv    = (const float*)d_in[4];
    const float* wo    = (const float*)d_in[5];
    const float* qnw   = (const float*)d_in[6];
    const float* knw   = (const float*)d_in[7];
    const float* lam   = (const float*)d_in[8];
    float* out = (float*)d_out;

    const int T = B_ * S_;
    char* ws = (char*)d_ws;
    size_t off = 0;
    auto alloc = [&](size_t bytes) {
        void* p = ws + off;
        off += (bytes + 255) & ~(size_t)255;
        return p;
    };
    __hip_bfloat16* xb   = (__hip_bfloat16*)alloc((size_t)T * D_ * 2);
    __hip_bfloat16* wcat = (__hip_bfloat16*)alloc((size_t)NCAT * D_ * 2);
    __hip_bfloat16* wob  = (__hip_bfloat16*)alloc((size_t)D_ * D_ * 2);
    __hip_bfloat16* qb16 = (__hip_bfloat16*)alloc((size_t)T * 2 * H_ * HD_ * 2);
    __hip_bfloat16* kb16 = (__hip_bfloat16*)alloc((size_t)T * 2 * KV_ * HD_ * 2);
    __hip_bfloat16* vT   = (__hip_bfloat16*)alloc((size_t)B_ * KV_ * HD_ * S_ * 2);
    unsigned* part = (unsigned*)alloc((size_t)256 * 2 * 8192 * 4);
    float* lpart   = (float*)alloc((size_t)256 * 2 * 2 * 128 * 4);
    __hip_bfloat16* aob  = xb;   // xb dead after QKV GEMM; same size

    // fused cvt: x, wq, wk, wv, wo (wcat segments are contiguous)
    cvt5_kernel<<<dim3(2048, 5), 256, 0, stream>>>(
        x, wq, wk, wv, wo,
        xb, wcat, wcat + (size_t)2 * H_ * HD_ * D_,
        wcat + (size_t)(2 * H_ * HD_ + 2 * KV_ * HD_) * D_, wob,
        T * D_, 2 * H_ * HD_ * D_, 2 * KV_ * HD_ * D_, KV_ * HD_ * D_, D_ * D_);

    // fused QKV projection + RMSNorm + RoPE + V-transpose
    gemm_qkv_fused<<<dim3(NCAT / 128, T / 128), 256, 0, stream>>>(
        (const short*)xb, (const short*)wcat, qb16, kb16, vT,
        freqs, qnw, knw, T, NCAT, D_);

    // differential causal attention + merge
    attn_kernel<<<512, 512, 0, stream>>>(
        (const short*)qb16, (const short*)kb16, (const short*)vT, aob, part, lpart, lam);
    attn_merge_kernel<<<512, 256, 0, stream>>>(part, lpart, aob, lam);

    // output projection -> f32 (128x64 tiles, 512 blocks = 2/CU)
    gemm_bt_n64<<<dim3(D_ / 64, T / 128), 256, 0, stream>>>(
        (const short*)aob, (const short*)wob, out, T, D_, D_);
}